// Round 3
// baseline (1946.770 us; speedup 1.0000x reference)
//
#include <hip/hip_runtime.h>
#include <math.h>

#define T_OBS 8
#define PRED_LEN 12
#define NSC 512
#define NPED 64
#define NTOT (NSC*NPED)
#define EPS 1e-5

// ---- ws double-region offsets (in doubles) ----
#define O_PWTP   0        // pred whh packed [8][80][40]
#define O_PWIH   25600    // pred wih [320][2]
#define O_PB     26240    // pred bih+bhh [320]
#define O_PLNG   26560
#define O_PLNB   26640
#define O_PWOUT  26720    // [2][80]
#define O_PBOUT  26880    // [2]
#define O_TWIH   26884    // traj wih [128][2]
#define O_TWP    27140    // traj whh packed [8][32][16]
#define O_TB     31236    // traj bih+bhh [128]
#define O_GWIP   31364    // graph wih packed [8][32][16]
#define O_GWHP   35460    // graph whh packed [8][32][16]
#define O_GB     39556    // graph bih+bhh [128]
#define O_GLNG   39684
#define O_GLNB   39716
#define O_W0     39748    // gat w0 [4][32][16]
#define O_A0S    41796
#define O_A0D    41860
#define O_B0     41924
#define O_W1     41940    // gat w1 [64][32]
#define O_A1S    43988
#define O_A1D    44020
#define O_B1     44052
#define D_TOTAL  44100

// ---------- fast fp64 math (rel err ~1e-16, far below the ~1e-10 budget) ----------
__device__ __forceinline__ double fast_exp(double x){
  x = fmin(fmax(x, -708.0), 708.0);
  const double L2E  = 1.4426950408889634074;
  const double LN2H = 6.93147180369123816490e-01;
  const double LN2L = 1.90821492927058770002e-10;
  double t = x*L2E;
  double n = rint(t);
  int ni = (int)n;
  double r = __builtin_fma(-n, LN2H, x);
  r = __builtin_fma(-n, LN2L, r);
  double p = 2.08767569878681e-09;            // 1/12!
  p = __builtin_fma(p, r, 2.505210838544172e-08);
  p = __builtin_fma(p, r, 2.755731922398589e-07);
  p = __builtin_fma(p, r, 2.755731922398589e-06);
  p = __builtin_fma(p, r, 2.480158730158730e-05);
  p = __builtin_fma(p, r, 1.984126984126984e-04);
  p = __builtin_fma(p, r, 1.388888888888889e-03);
  p = __builtin_fma(p, r, 8.333333333333333e-03);
  p = __builtin_fma(p, r, 4.166666666666667e-02);
  p = __builtin_fma(p, r, 1.666666666666667e-01);
  p = __builtin_fma(p, r, 0.5);
  p = __builtin_fma(p, r, 1.0);
  p = __builtin_fma(p, r, 1.0);
  double s = __hiloint2double((ni + 1023) << 20, 0);
  return p*s;
}
__device__ __forceinline__ double fast_rcp(double d){
#if __has_builtin(__builtin_amdgcn_rcp)
  double r = __builtin_amdgcn_rcp(d);
#else
  double r = 1.0/d;
#endif
  // 3 Newton iters: converges to <1ulp even from a coarse seed
  double e = __builtin_fma(-d, r, 1.0); r = __builtin_fma(r, e, r);
  e = __builtin_fma(-d, r, 1.0); r = __builtin_fma(r, e, r);
  e = __builtin_fma(-d, r, 1.0); r = __builtin_fma(r, e, r);
  return r;
}
__device__ __forceinline__ double fsig(double x){
  double xc = fmin(fmax(x, -40.0), 40.0);
  return fast_rcp(1.0 + fast_exp(-xc));
}
__device__ __forceinline__ double ftanh(double x){
  double xc = fmin(fmax(x, -20.0), 20.0);
  return __builtin_fma(-2.0, fast_rcp(1.0 + fast_exp(2.0*xc)), 1.0);
}

// ---------------- prep: fp64 conversion + per-wave-contiguous weight packing ----------------
__global__ void k_prep(
    const float* __restrict__ pwhh, const float* __restrict__ pwih,
    const float* __restrict__ pbih, const float* __restrict__ pbhh,
    const float* __restrict__ plng, const float* __restrict__ plnb,
    const float* __restrict__ pwout, const float* __restrict__ pbout,
    const float* __restrict__ twih, const float* __restrict__ twhh,
    const float* __restrict__ tbih, const float* __restrict__ tbhh,
    const float* __restrict__ gwih, const float* __restrict__ gwhh,
    const float* __restrict__ gbih, const float* __restrict__ gbhh,
    const float* __restrict__ glng, const float* __restrict__ glnb,
    const float* __restrict__ w0, const float* __restrict__ a0s,
    const float* __restrict__ a0d, const float* __restrict__ b0,
    const float* __restrict__ w1, const float* __restrict__ a1s,
    const float* __restrict__ a1d, const float* __restrict__ b1,
    double* __restrict__ wsd)
{
  int i = blockIdx.x*256 + threadIdx.x;
  if (i < 25600){
    int wv = i/3200, rem = i - wv*3200;
    int k = rem/40, j4 = rem - k*40;
    int j = j4>>2, g = j4&3;
    int row = g*80 + wv*10 + j;
    wsd[O_PWTP + i] = (double)pwhh[row*80 + k];
  }
  if (i < 640)  wsd[O_PWIH + i] = (double)pwih[i];
  if (i < 320)  wsd[O_PB + i] = (double)pbih[i] + (double)pbhh[i];
  if (i < 80){ wsd[O_PLNG + i] = (double)plng[i]; wsd[O_PLNB + i] = (double)plnb[i]; }
  if (i < 160) wsd[O_PWOUT + i] = (double)pwout[i];
  if (i < 2)   wsd[O_PBOUT + i] = (double)pbout[i];
  if (i < 256) wsd[O_TWIH + i] = (double)twih[i];
  if (i < 4096){
    int wv = i>>9, rem = i&511;
    int k = rem>>4, j4 = rem&15;
    int j = j4>>2, g = j4&3;
    int row = g*32 + wv*4 + j;
    wsd[O_TWP  + i] = (double)twhh[row*32 + k];
    wsd[O_GWIP + i] = (double)gwih[row*32 + k];
    wsd[O_GWHP + i] = (double)gwhh[row*32 + k];
  }
  if (i < 128){
    wsd[O_TB + i] = (double)tbih[i] + (double)tbhh[i];
    wsd[O_GB + i] = (double)gbih[i] + (double)gbhh[i];
  }
  if (i < 32){
    wsd[O_GLNG + i] = (double)glng[i]; wsd[O_GLNB + i] = (double)glnb[i];
    wsd[O_A1S + i] = (double)a1s[i]; wsd[O_A1D + i] = (double)a1d[i];
    wsd[O_B1 + i] = (double)b1[i];
  }
  if (i < 2048){ wsd[O_W0 + i] = (double)w0[i]; wsd[O_W1 + i] = (double)w1[i]; }
  if (i < 64){ wsd[O_A0S + i] = (double)a0s[i]; wsd[O_A0D + i] = (double)a0d[i]; }
  if (i < 16) wsd[O_B0 + i] = (double)b0[i];
}

// ---------------- K1: traj LSTM (2->32), 512 thr = 8 waves x 4 units ----------------
__global__ __launch_bounds__(512) void k_traj(
    const float* __restrict__ obs, const float* __restrict__ h0,
    const float* __restrict__ c0, const double* __restrict__ wsd,
    float* __restrict__ traj_hs)
{
  __shared__ double hdl[2048];           // [unit][ped]
  const double* wih = wsd + O_TWIH;
  const double* wp  = wsd + O_TWP;
  const double* bd  = wsd + O_TB;
  const int tid = threadIdx.x, lane = tid & 63;
  const int wv = __builtin_amdgcn_readfirstlane(tid >> 6);
  const int ub = wv*4;
  const int ped0 = blockIdx.x*64, ped = ped0 + lane;
  for (int idx = tid; idx < 2048; idx += 512){
    int f = idx>>6, p = idx&63;
    hdl[idx] = (double)h0[(ped0+p)*32 + f];
  }
  double c[4];
  #pragma unroll
  for (int j = 0; j < 4; ++j) c[j] = (double)c0[ped*32 + ub + j];
  __syncthreads();

  for (int t = 0; t < T_OBS; ++t){
    double x0 = (double)obs[((size_t)t*NTOT + ped)*2 + 0];
    double x1 = (double)obs[((size_t)t*NTOT + ped)*2 + 1];
    double acc[16];
    #pragma unroll
    for (int j = 0; j < 4; ++j){
      #pragma unroll
      for (int g = 0; g < 4; ++g){
        int r = g*32 + ub + j;
        acc[j*4+g] = bd[r] + wih[r*2+0]*x0 + wih[r*2+1]*x1;
      }
    }
    for (int k = 0; k < 32; ++k){
      double hk = hdl[k*64 + lane];
      const double* wr = wp + (wv*32 + k)*16;
      #pragma unroll
      for (int j4 = 0; j4 < 16; ++j4) acc[j4] += wr[j4]*hk;
    }
    double hn[4];
    #pragma unroll
    for (int j = 0; j < 4; ++j){
      double ig = fsig(acc[j*4+0]);
      double fg = fsig(acc[j*4+1]);
      double gg = ftanh(acc[j*4+2]);
      double og = fsig(acc[j*4+3]);
      c[j] = fg*c[j] + ig*gg;
      hn[j] = og*ftanh(c[j]);
    }
    __syncthreads();
    #pragma unroll
    for (int j = 0; j < 4; ++j){
      hdl[(ub+j)*64 + lane] = hn[j];
      traj_hs[((size_t)t*NTOT + ped)*32 + ub + j] = (float)hn[j];
    }
    __syncthreads();
  }
}

// ---------------- K2: GAT encoder ----------------
__global__ __launch_bounds__(256) void k_gat(
    const float* __restrict__ ths, const double* __restrict__ wsd,
    float* __restrict__ gout)
{
  __shared__ float xA[64*65];
  __shared__ double hpB[64*68];
  __shared__ double as0[256], ad0[256];
  __shared__ double as1[64], ad1[64], Ziv[64], mn[64], rs[64];

  const double* w0  = wsd + O_W0;
  const double* a0s = wsd + O_A0S;
  const double* a0d = wsd + O_A0D;
  const double* b0  = wsd + O_B0;
  const double* w1  = wsd + O_W1;
  const double* a1s = wsd + O_A1S;
  const double* a1d = wsd + O_A1D;
  const double* b1  = wsd + O_B1;

  const int tid = threadIdx.x;
  const int sb = blockIdx.x >> 3, tb = blockIdx.x & 7;
  const int n = tid & 63;
  const int q = __builtin_amdgcn_readfirstlane(tid >> 6);

  const float* xin = ths + ((size_t)tb*NTOT + sb*64)*32;
  for (int idx = tid; idx < 2048; idx += 256)
    xA[(idx>>5)*65 + (idx&31)] = xin[idx];
  __syncthreads();
  if (tid < 32){
    double s1 = 0, s2 = 0;
    for (int p = 0; p < 64; ++p){ double v = xA[p*65+tid]; s1 += v; s2 += v*v; }
    double mu = s1*(1.0/64.0), va = s2*(1.0/64.0) - mu*mu;
    mn[tid] = mu; rs[tid] = 1.0/sqrt(va + EPS);
  }
  __syncthreads();
  for (int idx = tid; idx < 2048; idx += 256){
    int p = idx>>5, f = idx&31;
    xA[p*65+f] = (float)(((double)xA[p*65+f] - mn[f])*rs[f]);
  }
  __syncthreads();
  { // hp0 + attn dots
    double acc[16];
    #pragma unroll
    for (int o = 0; o < 16; ++o) acc[o] = 0;
    for (int f = 0; f < 32; ++f){
      double xv = (double)xA[n*65+f];
      const double* wr = w0 + (q*32+f)*16;
      #pragma unroll
      for (int o = 0; o < 16; ++o) acc[o] += xv*wr[o];
    }
    double sa = 0, sd = 0;
    #pragma unroll
    for (int o = 0; o < 16; ++o){
      sa += acc[o]*a0s[q*16+o];
      sd += acc[o]*a0d[q*16+o];
      hpB[n*68 + q*16 + o] = acc[o];
    }
    as0[q*64+n] = sa; ad0[q*64+n] = sd;
  }
  __syncthreads();
  { // attn L0 softmax + aggregate + bias + ELU
    double arow = as0[q*64+n];
    double mx = -1e300;
    for (int m2 = 0; m2 < 64; ++m2){
      double e = arow + ad0[q*64+m2];
      double lr = e > 0 ? e : 0.2*e;
      mx = fmax(mx, lr);
    }
    double num[16];
    #pragma unroll
    for (int o = 0; o < 16; ++o) num[o] = 0;
    double Z = 0;
    for (int m2 = 0; m2 < 64; ++m2){
      double e = arow + ad0[q*64+m2];
      double lr = e > 0 ? e : 0.2*e;
      double pv = fast_exp(lr - mx);
      Z += pv;
      const double2* h2 = (const double2*)&hpB[m2*68 + q*16];
      #pragma unroll
      for (int o2 = 0; o2 < 8; ++o2){
        double2 v = h2[o2];
        num[o2*2+0] += pv*v.x; num[o2*2+1] += pv*v.y;
      }
    }
    double iZ = fast_rcp(Z);
    #pragma unroll
    for (int o = 0; o < 16; ++o){
      double y = num[o]*iZ + b0[o];
      xA[n*65 + q*16 + o] = (float)(y > 0 ? y : fast_exp(y)-1.0);
    }
  }
  __syncthreads();
  if (tid < 64){
    double s1 = 0, s2 = 0;
    for (int p = 0; p < 64; ++p){ double v = xA[p*65+tid]; s1 += v; s2 += v*v; }
    double mu = s1*(1.0/64.0), va = s2*(1.0/64.0) - mu*mu;
    mn[tid] = mu; rs[tid] = 1.0/sqrt(va + EPS);
  }
  __syncthreads();
  for (int idx = tid; idx < 4096; idx += 256){
    int p = idx>>6, f = idx&63;
    xA[p*65+f] = (float)(((double)xA[p*65+f] - mn[f])*rs[f]);
  }
  __syncthreads();
  { // hp1
    double a8[8];
    #pragma unroll
    for (int j = 0; j < 8; ++j) a8[j] = 0;
    for (int f = 0; f < 64; ++f){
      double xv = (double)xA[n*65+f];
      const double* wr = w1 + f*32 + q*8;
      #pragma unroll
      for (int j = 0; j < 8; ++j) a8[j] += xv*wr[j];
    }
    #pragma unroll
    for (int j = 0; j < 8; ++j) hpB[n*68 + q*8 + j] = a8[j];
  }
  __syncthreads();
  if (tid < 64){
    double sa = 0, sd = 0;
    for (int o = 0; o < 32; ++o){
      double v = hpB[tid*68 + o];
      sa += v*a1s[o]; sd += v*a1d[o];
    }
    as1[tid] = sa; ad1[tid] = sd;
  }
  __syncthreads();
  if (tid < 64){
    double arow = as1[tid];
    double mx = -1e300;
    for (int m2 = 0; m2 < 64; ++m2){
      double e = arow + ad1[m2];
      double lr = e > 0 ? e : 0.2*e;
      mx = fmax(mx, lr);
    }
    double Z = 0;
    for (int m2 = 0; m2 < 64; ++m2){
      double e = arow + ad1[m2];
      double lr = e > 0 ? e : 0.2*e;
      double pv = fast_exp(lr - mx);
      xA[tid*65+m2] = (float)pv;
      Z += pv;
    }
    Ziv[tid] = fast_rcp(Z);
  }
  __syncthreads();
  { // aggregate L1, write gin as [t][scene][f][ped]
    double a8[8];
    #pragma unroll
    for (int j = 0; j < 8; ++j) a8[j] = 0;
    for (int m2 = 0; m2 < 64; ++m2){
      double av = (double)xA[n*65+m2];
      const double2* h2 = (const double2*)&hpB[m2*68 + q*8];
      double2 v0 = h2[0], v1 = h2[1], v2 = h2[2], v3 = h2[3];
      a8[0] += av*v0.x; a8[1] += av*v0.y; a8[2] += av*v1.x; a8[3] += av*v1.y;
      a8[4] += av*v2.x; a8[5] += av*v2.y; a8[6] += av*v3.x; a8[7] += av*v3.y;
    }
    double iZ = Ziv[n];
    float* go = gout + ((size_t)(tb*NSC + sb)*32)*64;
    #pragma unroll
    for (int j = 0; j < 8; ++j)
      go[(q*8+j)*64 + n] = (float)(a8[j]*iZ + b1[q*8+j]);
  }
}

// ---------------- K3: graph LSTM (32->32) + LN, 512 thr = 8 waves x 4 units ----------------
__global__ __launch_bounds__(512) void k_graph(
    const float* __restrict__ gin, const float* __restrict__ h0,
    const float* __restrict__ c0, const double* __restrict__ wsd,
    float* __restrict__ gh)
{
  __shared__ double hdl[2048];
  __shared__ double xld[2048];
  __shared__ double ps[512], pq[512];
  const double* wip = wsd + O_GWIP;
  const double* whp = wsd + O_GWHP;
  const double* bd  = wsd + O_GB;
  const double* lng = wsd + O_GLNG;
  const double* lnb = wsd + O_GLNB;
  const int tid = threadIdx.x, lane = tid & 63;
  const int wv = __builtin_amdgcn_readfirstlane(tid >> 6);
  const int ub = wv*4;
  const int sb = blockIdx.x, ped0 = sb*64, ped = ped0 + lane;
  for (int idx = tid; idx < 2048; idx += 512){
    int f = idx>>6, p = idx&63;
    hdl[idx] = (double)h0[(ped0+p)*32 + f];
  }
  double c[4];
  #pragma unroll
  for (int j = 0; j < 4; ++j) c[j] = (double)c0[ped*32 + ub + j];
  __syncthreads();

  for (int t = 0; t < T_OBS; ++t){
    const float* gb = gin + (size_t)(t*NSC + sb)*2048;
    for (int idx = tid; idx < 2048; idx += 512) xld[idx] = (double)gb[idx];
    __syncthreads();
    double acc[16];
    #pragma unroll
    for (int j = 0; j < 4; ++j){
      #pragma unroll
      for (int g = 0; g < 4; ++g) acc[j*4+g] = bd[g*32 + ub + j];
    }
    for (int k = 0; k < 32; ++k){
      double xk = xld[k*64 + lane];
      double hk = hdl[k*64 + lane];
      const double* wi = wip + (wv*32 + k)*16;
      const double* wh = whp + (wv*32 + k)*16;
      #pragma unroll
      for (int j4 = 0; j4 < 16; ++j4) acc[j4] += wi[j4]*xk + wh[j4]*hk;
    }
    double hp[4]; double s1 = 0, s2 = 0;
    #pragma unroll
    for (int j = 0; j < 4; ++j){
      double ig = fsig(acc[j*4+0]);
      double fg = fsig(acc[j*4+1]);
      double gg = ftanh(acc[j*4+2]);
      double og = fsig(acc[j*4+3]);
      c[j] = fg*c[j] + ig*gg;
      hp[j] = og*ftanh(c[j]);
      s1 += hp[j]; s2 += hp[j]*hp[j];
    }
    ps[wv*64+lane] = s1; pq[wv*64+lane] = s2;
    __syncthreads();
    double sa = 0, sq = 0;
    #pragma unroll
    for (int w = 0; w < 8; ++w){ sa += ps[w*64+lane]; sq += pq[w*64+lane]; }
    double mu = sa*(1.0/32.0);
    double va = sq*(1.0/32.0) - mu*mu;
    double ri = 1.0/sqrt(va + EPS);
    #pragma unroll
    for (int j = 0; j < 4; ++j){
      int u = ub + j;
      double hn = (hp[j]-mu)*ri*lng[u] + lnb[u];
      hdl[u*64 + lane] = hn;
      if (t == T_OBS-1) gh[ped*32 + u] = (float)hn;
    }
    __syncthreads();
  }
}

// ---------------- K4: pred LSTM (2->80) + LN + head, 512 thr = 8 waves x 10 units ----------------
__global__ __launch_bounds__(512) void k_pred(
    const float* __restrict__ traj_hs, const float* __restrict__ gh,
    const float* __restrict__ zn, const float* __restrict__ obs,
    const double* __restrict__ wsd, float* __restrict__ outm)
{
  __shared__ double hd[80*64];
  __shared__ double ps[512], pq[512];
  __shared__ double po[512*2];
  const double* wTp  = wsd + O_PWTP;
  const double* wih  = wsd + O_PWIH;
  const double* bd   = wsd + O_PB;
  const double* lng  = wsd + O_PLNG;
  const double* lnb  = wsd + O_PLNB;
  const double* wout = wsd + O_PWOUT;
  const double* bout = wsd + O_PBOUT;
  const int tid = threadIdx.x, lane = tid & 63;
  const int wv = __builtin_amdgcn_readfirstlane(tid >> 6);
  const int ub = wv*10;
  const int scene = blockIdx.x, ped0 = scene*64, ped = ped0 + lane;

  for (int idx = tid; idx < 5120; idx += 512){
    int f = idx>>6, p = idx&63;
    float v;
    if (f < 32)      v = traj_hs[((size_t)7*NTOT + ped0 + p)*32 + f];
    else if (f < 64) v = gh[(ped0+p)*32 + (f-32)];
    else             v = zn[scene*16 + (f-64)];
    hd[idx] = (double)v;
  }
  double c[10];
  #pragma unroll
  for (int j = 0; j < 10; ++j) c[j] = 0.0;
  double x0 = (double)obs[((size_t)7*NTOT + ped)*2 + 0];
  double x1 = (double)obs[((size_t)7*NTOT + ped)*2 + 1];
  __syncthreads();

  for (int t = 0; t < PRED_LEN; ++t){
    double acc[40];
    #pragma unroll
    for (int j = 0; j < 10; ++j){
      #pragma unroll
      for (int g = 0; g < 4; ++g){
        int r = g*80 + ub + j;
        acc[j*4+g] = bd[r] + wih[r*2+0]*x0 + wih[r*2+1]*x1;
      }
    }
    for (int k = 0; k < 80; ++k){
      double hk = hd[k*64 + lane];
      const double* wr = wTp + (wv*80 + k)*40;
      #pragma unroll
      for (int j4 = 0; j4 < 40; ++j4) acc[j4] += wr[j4]*hk;
    }
    double hp[10]; double s1 = 0, s2 = 0;
    #pragma unroll
    for (int j = 0; j < 10; ++j){
      double ig = fsig(acc[j*4+0]);
      double fg = fsig(acc[j*4+1]);
      double gg = ftanh(acc[j*4+2]);
      double og = fsig(acc[j*4+3]);
      c[j] = fg*c[j] + ig*gg;
      hp[j] = og*ftanh(c[j]);
      s1 += hp[j]; s2 += hp[j]*hp[j];
    }
    ps[wv*64+lane] = s1; pq[wv*64+lane] = s2;
    __syncthreads();
    double sa = 0, sq = 0;
    #pragma unroll
    for (int w = 0; w < 8; ++w){ sa += ps[w*64+lane]; sq += pq[w*64+lane]; }
    double mu = sa*(1.0/80.0);
    double va = sq*(1.0/80.0) - mu*mu;
    double ri = 1.0/sqrt(va + EPS);
    double p0 = 0, p1 = 0;
    #pragma unroll
    for (int j = 0; j < 10; ++j){
      int u = ub + j;
      double hn = (hp[j]-mu)*ri*lng[u] + lnb[u];
      hd[u*64 + lane] = hn;
      p0 += hn*wout[u];
      p1 += hn*wout[80+u];
    }
    po[(wv*64+lane)*2+0] = p0; po[(wv*64+lane)*2+1] = p1;
    __syncthreads();
    double o0 = bout[0], o1 = bout[1];
    #pragma unroll
    for (int w = 0; w < 8; ++w){ o0 += po[(w*64+lane)*2+0]; o1 += po[(w*64+lane)*2+1]; }
    x0 = o0; x1 = o1;
    if (wv == 0){
      outm[((size_t)t*NTOT + ped)*2 + 0] = (float)x0;
      outm[((size_t)t*NTOT + ped)*2 + 1] = (float)x1;
    }
  }
}

// ---------------- K5: constant log_std / std outputs ----------------
__global__ void k_fill(const float* __restrict__ als, float* __restrict__ out) {
  const int M = PRED_LEN*NTOT*2;
  float l0 = als[0], l1 = als[1];
  float e0 = (float)exp((double)l0), e1 = (float)exp((double)l1);
  for (int i = blockIdx.x*256 + threadIdx.x; i < M; i += gridDim.x*256) {
    float lv = (i & 1) ? l1 : l0;
    float ev = (i & 1) ? e1 : e0;
    out[M + i]   = lv;
    out[2*M + i] = ev;
  }
}

extern "C" void kernel_launch(void* const* d_in, const int* in_sizes, int n_in,
                              void* d_out, int out_size, void* d_ws, size_t ws_size,
                              hipStream_t stream)
{
  const float* obs   = (const float*)d_in[0];
  const float* zn    = (const float*)d_in[2];
  const float* th0   = (const float*)d_in[3];
  const float* tc0   = (const float*)d_in[4];
  const float* gh0   = (const float*)d_in[5];
  const float* gc0   = (const float*)d_in[6];
  const float* gw0   = (const float*)d_in[7];
  const float* gas0  = (const float*)d_in[8];
  const float* gad0  = (const float*)d_in[9];
  const float* gb0   = (const float*)d_in[10];
  const float* gw1   = (const float*)d_in[11];
  const float* gas1  = (const float*)d_in[12];
  const float* gad1  = (const float*)d_in[13];
  const float* gb1   = (const float*)d_in[14];
  const float* twih  = (const float*)d_in[15];
  const float* twhh  = (const float*)d_in[16];
  const float* tbih  = (const float*)d_in[17];
  const float* tbhh  = (const float*)d_in[18];
  const float* gwih  = (const float*)d_in[19];
  const float* gwhh  = (const float*)d_in[20];
  const float* gbih  = (const float*)d_in[21];
  const float* gbhh  = (const float*)d_in[22];
  const float* glng  = (const float*)d_in[23];
  const float* glnb  = (const float*)d_in[24];
  const float* pwih  = (const float*)d_in[25];
  const float* pwhh  = (const float*)d_in[26];
  const float* pbih  = (const float*)d_in[27];
  const float* pbhh  = (const float*)d_in[28];
  const float* plng  = (const float*)d_in[29];
  const float* plnb  = (const float*)d_in[30];
  const float* poww  = (const float*)d_in[31];
  const float* pob   = (const float*)d_in[32];
  const float* als   = (const float*)d_in[33];

  float* out = (float*)d_out;
  double* wsd = (double*)d_ws;
  float* traj_hs = (float*)(wsd + D_TOTAL);         // [8][NTOT][32]
  float* gin     = traj_hs + (size_t)8*NTOT*32;     // [8][NSC][32][64]
  float* gh      = gin + (size_t)8*NTOT*32;         // [NTOT][32]

  k_prep<<<dim3(104), dim3(256), 0, stream>>>(
      pwhh, pwih, pbih, pbhh, plng, plnb, poww, pob,
      twih, twhh, tbih, tbhh, gwih, gwhh, gbih, gbhh, glng, glnb,
      gw0, gas0, gad0, gb0, gw1, gas1, gad1, gb1, wsd);
  k_traj<<<dim3(512), dim3(512), 0, stream>>>(obs, th0, tc0, wsd, traj_hs);
  k_gat<<<dim3(4096), dim3(256), 0, stream>>>(traj_hs, wsd, gin);
  k_graph<<<dim3(512), dim3(512), 0, stream>>>(gin, gh0, gc0, wsd, gh);
  k_pred<<<dim3(512), dim3(512), 0, stream>>>(traj_hs, gh, zn, obs, wsd, out);
  k_fill<<<dim3(1024), dim3(256), 0, stream>>>(als, out);
}

// Round 4
// 1459.071 us; speedup vs baseline: 1.3343x; 1.3343x over previous
//
#include <hip/hip_runtime.h>
#include <math.h>

#define T_OBS 8
#define PRED_LEN 12
#define NSC 512
#define NPED 64
#define NTOT (NSC*NPED)
#define EPS 1e-5

// ---- ws double-region offsets (in doubles) ----
#define O_PWT    0        // pred whh^T [80][320]
#define O_PWIH   25600    // pred wih [320][2]
#define O_PB     26240    // pred bih+bhh [320]
#define O_PLNG   26560
#define O_PLNB   26640
#define O_PWOUT  26720    // [2][80]
#define O_PBOUT  26880    // [2]
#define O_TWIH   26884    // traj wih [128][2]
#define O_TWHHT  27140    // traj whh^T [32][128]
#define O_TB     31236    // traj bih+bhh [128]
#define O_GWIHT  31364    // graph wih^T [32][128]
#define O_GWHHT  35460    // graph whh^T [32][128]
#define O_GB     39556    // graph bih+bhh [128]
#define O_GLNG   39684
#define O_GLNB   39716
#define O_W0     39748    // gat w0 [4][32][16]
#define O_A0S    41796
#define O_A0D    41860
#define O_B0     41924
#define O_W1     41940    // gat w1 [64][32]
#define O_A1S    43988
#define O_A1D    44020
#define O_B1     44052
#define D_TOTAL  44100

// ---------- fast fp64 math (rel err ~1e-16; validated bit-identical absmax in R3) ----------
__device__ __forceinline__ double fast_exp(double x){
  x = fmin(fmax(x, -708.0), 708.0);
  const double L2E  = 1.4426950408889634074;
  const double LN2H = 6.93147180369123816490e-01;
  const double LN2L = 1.90821492927058770002e-10;
  double t = x*L2E;
  double n = rint(t);
  int ni = (int)n;
  double r = __builtin_fma(-n, LN2H, x);
  r = __builtin_fma(-n, LN2L, r);
  double p = 2.08767569878681e-09;            // 1/12!
  p = __builtin_fma(p, r, 2.505210838544172e-08);
  p = __builtin_fma(p, r, 2.755731922398589e-07);
  p = __builtin_fma(p, r, 2.755731922398589e-06);
  p = __builtin_fma(p, r, 2.480158730158730e-05);
  p = __builtin_fma(p, r, 1.984126984126984e-04);
  p = __builtin_fma(p, r, 1.388888888888889e-03);
  p = __builtin_fma(p, r, 8.333333333333333e-03);
  p = __builtin_fma(p, r, 4.166666666666667e-02);
  p = __builtin_fma(p, r, 1.666666666666667e-01);
  p = __builtin_fma(p, r, 0.5);
  p = __builtin_fma(p, r, 1.0);
  p = __builtin_fma(p, r, 1.0);
  double s = __hiloint2double((ni + 1023) << 20, 0);
  return p*s;
}
__device__ __forceinline__ double fast_rcp(double d){
#if __has_builtin(__builtin_amdgcn_rcp)
  double r = __builtin_amdgcn_rcp(d);
#else
  double r = 1.0/d;
#endif
  double e = __builtin_fma(-d, r, 1.0); r = __builtin_fma(r, e, r);
  e = __builtin_fma(-d, r, 1.0); r = __builtin_fma(r, e, r);
  e = __builtin_fma(-d, r, 1.0); r = __builtin_fma(r, e, r);
  return r;
}
__device__ __forceinline__ double fast_rsqrt(double d){
#if __has_builtin(__builtin_amdgcn_rsq)
  double r = __builtin_amdgcn_rsq(d);
#else
  double r = 1.0/sqrt(d);
#endif
  double hr = 0.5*d;
  r = r*__builtin_fma(-hr*r, r, 1.5);
  r = r*__builtin_fma(-hr*r, r, 1.5);
  r = r*__builtin_fma(-hr*r, r, 1.5);
  return r;
}
__device__ __forceinline__ double fsig(double x){
  double xc = fmin(fmax(x, -40.0), 40.0);
  return fast_rcp(1.0 + fast_exp(-xc));
}
__device__ __forceinline__ double ftanh(double x){
  double xc = fmin(fmax(x, -20.0), 20.0);
  return __builtin_fma(-2.0, fast_rcp(1.0 + fast_exp(2.0*xc)), 1.0);
}

// ---------------- prep: convert all weights to fp64 (and transpose whh's) ----------------
__global__ void k_prep(
    const float* __restrict__ pwhh, const float* __restrict__ pwih,
    const float* __restrict__ pbih, const float* __restrict__ pbhh,
    const float* __restrict__ plng, const float* __restrict__ plnb,
    const float* __restrict__ pwout, const float* __restrict__ pbout,
    const float* __restrict__ twih, const float* __restrict__ twhh,
    const float* __restrict__ tbih, const float* __restrict__ tbhh,
    const float* __restrict__ gwih, const float* __restrict__ gwhh,
    const float* __restrict__ gbih, const float* __restrict__ gbhh,
    const float* __restrict__ glng, const float* __restrict__ glnb,
    const float* __restrict__ w0, const float* __restrict__ a0s,
    const float* __restrict__ a0d, const float* __restrict__ b0,
    const float* __restrict__ w1, const float* __restrict__ a1s,
    const float* __restrict__ a1d, const float* __restrict__ b1,
    double* __restrict__ wsd)
{
  int i = blockIdx.x*256 + threadIdx.x;
  if (i < 25600){ int r = i/80, k = i - r*80; wsd[O_PWT + k*320 + r] = (double)pwhh[i]; }
  if (i < 640)  wsd[O_PWIH + i] = (double)pwih[i];
  if (i < 320)  wsd[O_PB + i] = (double)pbih[i] + (double)pbhh[i];
  if (i < 80){ wsd[O_PLNG + i] = (double)plng[i]; wsd[O_PLNB + i] = (double)plnb[i]; }
  if (i < 160) wsd[O_PWOUT + i] = (double)pwout[i];
  if (i < 2)   wsd[O_PBOUT + i] = (double)pbout[i];
  if (i < 256) wsd[O_TWIH + i] = (double)twih[i];
  if (i < 4096){
    int r = i>>5, k = i&31;
    wsd[O_TWHHT + k*128 + r] = (double)twhh[i];
    wsd[O_GWIHT + k*128 + r] = (double)gwih[i];
    wsd[O_GWHHT + k*128 + r] = (double)gwhh[i];
  }
  if (i < 128){
    wsd[O_TB + i] = (double)tbih[i] + (double)tbhh[i];
    wsd[O_GB + i] = (double)gbih[i] + (double)gbhh[i];
  }
  if (i < 32){
    wsd[O_GLNG + i] = (double)glng[i]; wsd[O_GLNB + i] = (double)glnb[i];
    wsd[O_A1S + i] = (double)a1s[i]; wsd[O_A1D + i] = (double)a1d[i];
    wsd[O_B1 + i] = (double)b1[i];
  }
  if (i < 2048){ wsd[O_W0 + i] = (double)w0[i]; wsd[O_W1 + i] = (double)w1[i]; }
  if (i < 64){ wsd[O_A0S + i] = (double)a0s[i]; wsd[O_A0D + i] = (double)a0d[i]; }
  if (i < 16) wsd[O_B0 + i] = (double)b0[i];
}

// ---------------- K1: traj LSTM (2->32), fp64, 256 thr = 4 waves x 8 units ----------------
__global__ __launch_bounds__(256) void k_traj(
    const float* __restrict__ obs, const float* __restrict__ h0,
    const float* __restrict__ c0, const double* __restrict__ wsd,
    float* __restrict__ traj_hs)
{
  __shared__ double hdl[32*64];
  const double* wih  = wsd + O_TWIH;
  const double* whhT = wsd + O_TWHHT;
  const double* bd   = wsd + O_TB;
  const int tid = threadIdx.x, lane = tid & 63;
  const int wv = __builtin_amdgcn_readfirstlane(tid >> 6);
  const int ub = wv*8;
  const int ped0 = blockIdx.x*64, ped = ped0 + lane;
  for (int idx = tid; idx < 2048; idx += 256){
    int f = idx>>6, p = idx&63;
    hdl[idx] = (double)h0[(ped0+p)*32 + f];
  }
  double c[8];
  #pragma unroll
  for (int j = 0; j < 8; ++j) c[j] = (double)c0[ped*32 + ub + j];

  for (int t = 0; t < T_OBS; ++t){
    double x0 = (double)obs[((size_t)t*NTOT + ped)*2 + 0];
    double x1 = (double)obs[((size_t)t*NTOT + ped)*2 + 1];
    __syncthreads();
    double acc[32];
    #pragma unroll
    for (int j = 0; j < 8; ++j){
      #pragma unroll
      for (int g = 0; g < 4; ++g){
        int r = g*32 + ub + j;
        acc[j*4+g] = bd[r] + wih[r*2+0]*x0 + wih[r*2+1]*x1;
      }
    }
    for (int k = 0; k < 32; ++k){
      double hk = hdl[k*64 + lane];
      const double* wh = whhT + k*128;
      #pragma unroll
      for (int j = 0; j < 8; ++j){
        #pragma unroll
        for (int g = 0; g < 4; ++g) acc[j*4+g] += wh[g*32 + ub + j]*hk;
      }
    }
    double hn[8];
    #pragma unroll
    for (int j = 0; j < 8; ++j){
      double ig = fsig(acc[j*4+0]);
      double fg = fsig(acc[j*4+1]);
      double gg = ftanh(acc[j*4+2]);
      double og = fsig(acc[j*4+3]);
      c[j] = fg*c[j] + ig*gg;
      hn[j] = og*ftanh(c[j]);
    }
    __syncthreads();
    #pragma unroll
    for (int j = 0; j < 8; ++j){
      hdl[(ub+j)*64 + lane] = hn[j];
      traj_hs[((size_t)t*NTOT + ped)*32 + ub + j] = (float)hn[j];
    }
  }
}

// ---------------- K2: GAT encoder (fp64 compute, fp32 LDS x / probs) ----------------
__global__ __launch_bounds__(256) void k_gat(
    const float* __restrict__ ths, const double* __restrict__ wsd,
    float* __restrict__ gout)
{
  __shared__ float xA[64*65];
  __shared__ double hpB[64*68];
  __shared__ double as0[256], ad0[256];
  __shared__ double as1[64], ad1[64], Ziv[64], mn[64], rs[64];

  const double* w0  = wsd + O_W0;
  const double* a0s = wsd + O_A0S;
  const double* a0d = wsd + O_A0D;
  const double* b0  = wsd + O_B0;
  const double* w1  = wsd + O_W1;
  const double* a1s = wsd + O_A1S;
  const double* a1d = wsd + O_A1D;
  const double* b1  = wsd + O_B1;

  const int tid = threadIdx.x;
  const int sb = blockIdx.x >> 3, tb = blockIdx.x & 7;
  const int n = tid & 63;
  const int q = __builtin_amdgcn_readfirstlane(tid >> 6);

  const float* xin = ths + ((size_t)tb*NTOT + sb*64)*32;
  for (int idx = tid; idx < 2048; idx += 256)
    xA[(idx>>5)*65 + (idx&31)] = xin[idx];
  __syncthreads();
  if (tid < 32){
    double s1 = 0, s2 = 0;
    for (int p = 0; p < 64; ++p){ double v = xA[p*65+tid]; s1 += v; s2 += v*v; }
    double mu = s1*(1.0/64.0), va = s2*(1.0/64.0) - mu*mu;
    mn[tid] = mu; rs[tid] = fast_rsqrt(va + EPS);
  }
  __syncthreads();
  for (int idx = tid; idx < 2048; idx += 256){
    int p = idx>>5, f = idx&31;
    xA[p*65+f] = (float)(((double)xA[p*65+f] - mn[f])*rs[f]);
  }
  __syncthreads();
  { // hp0 + attn dots
    double acc[16];
    #pragma unroll
    for (int o = 0; o < 16; ++o) acc[o] = 0;
    for (int f = 0; f < 32; ++f){
      double xv = (double)xA[n*65+f];
      const double* wr = w0 + (q*32+f)*16;
      #pragma unroll
      for (int o = 0; o < 16; ++o) acc[o] += xv*wr[o];
    }
    double sa = 0, sd = 0;
    #pragma unroll
    for (int o = 0; o < 16; ++o){
      sa += acc[o]*a0s[q*16+o];
      sd += acc[o]*a0d[q*16+o];
      hpB[n*68 + q*16 + o] = acc[o];
    }
    as0[q*64+n] = sa; ad0[q*64+n] = sd;
  }
  __syncthreads();
  { // attn L0 softmax + aggregate + bias + ELU
    double arow = as0[q*64+n];
    double mx = -1e300;
    for (int m2 = 0; m2 < 64; ++m2){
      double e = arow + ad0[q*64+m2];
      double lr = e > 0 ? e : 0.2*e;
      mx = fmax(mx, lr);
    }
    double num[16];
    #pragma unroll
    for (int o = 0; o < 16; ++o) num[o] = 0;
    double Z = 0;
    for (int m2 = 0; m2 < 64; ++m2){
      double e = arow + ad0[q*64+m2];
      double lr = e > 0 ? e : 0.2*e;
      double pv = fast_exp(lr - mx);
      Z += pv;
      const double2* h2 = (const double2*)&hpB[m2*68 + q*16];
      #pragma unroll
      for (int o2 = 0; o2 < 8; ++o2){
        double2 v = h2[o2];
        num[o2*2+0] += pv*v.x; num[o2*2+1] += pv*v.y;
      }
    }
    double iZ = fast_rcp(Z);
    #pragma unroll
    for (int o = 0; o < 16; ++o){
      double y = num[o]*iZ + b0[o];
      xA[n*65 + q*16 + o] = (float)(y > 0 ? y : fast_exp(y)-1.0);
    }
  }
  __syncthreads();
  if (tid < 64){
    double s1 = 0, s2 = 0;
    for (int p = 0; p < 64; ++p){ double v = xA[p*65+tid]; s1 += v; s2 += v*v; }
    double mu = s1*(1.0/64.0), va = s2*(1.0/64.0) - mu*mu;
    mn[tid] = mu; rs[tid] = fast_rsqrt(va + EPS);
  }
  __syncthreads();
  for (int idx = tid; idx < 4096; idx += 256){
    int p = idx>>6, f = idx&63;
    xA[p*65+f] = (float)(((double)xA[p*65+f] - mn[f])*rs[f]);
  }
  __syncthreads();
  { // hp1
    double a8[8];
    #pragma unroll
    for (int j = 0; j < 8; ++j) a8[j] = 0;
    for (int f = 0; f < 64; ++f){
      double xv = (double)xA[n*65+f];
      const double* wr = w1 + f*32 + q*8;
      #pragma unroll
      for (int j = 0; j < 8; ++j) a8[j] += xv*wr[j];
    }
    #pragma unroll
    for (int j = 0; j < 8; ++j) hpB[n*68 + q*8 + j] = a8[j];
  }
  __syncthreads();
  if (tid < 64){
    double sa = 0, sd = 0;
    for (int o = 0; o < 32; ++o){
      double v = hpB[tid*68 + o];
      sa += v*a1s[o]; sd += v*a1d[o];
    }
    as1[tid] = sa; ad1[tid] = sd;
  }
  __syncthreads();
  if (tid < 64){
    double arow = as1[tid];
    double mx = -1e300;
    for (int m2 = 0; m2 < 64; ++m2){
      double e = arow + ad1[m2];
      double lr = e > 0 ? e : 0.2*e;
      mx = fmax(mx, lr);
    }
    double Z = 0;
    for (int m2 = 0; m2 < 64; ++m2){
      double e = arow + ad1[m2];
      double lr = e > 0 ? e : 0.2*e;
      double pv = fast_exp(lr - mx);
      xA[tid*65+m2] = (float)pv;
      Z += pv;
    }
    Ziv[tid] = fast_rcp(Z);
  }
  __syncthreads();
  { // aggregate L1, write gin as [t][scene][f][ped]
    double a8[8];
    #pragma unroll
    for (int j = 0; j < 8; ++j) a8[j] = 0;
    for (int m2 = 0; m2 < 64; ++m2){
      double av = (double)xA[n*65+m2];
      const double2* h2 = (const double2*)&hpB[m2*68 + q*8];
      double2 v0 = h2[0], v1 = h2[1], v2 = h2[2], v3 = h2[3];
      a8[0] += av*v0.x; a8[1] += av*v0.y; a8[2] += av*v1.x; a8[3] += av*v1.y;
      a8[4] += av*v2.x; a8[5] += av*v2.y; a8[6] += av*v3.x; a8[7] += av*v3.y;
    }
    double iZ = Ziv[n];
    float* go = gout + ((size_t)(tb*NSC + sb)*32)*64;
    #pragma unroll
    for (int j = 0; j < 8; ++j)
      go[(q*8+j)*64 + n] = (float)(a8[j]*iZ + b1[q*8+j]);
  }
}

// ---------------- K3: graph LSTM (32->32) + LN, fp64, 256 thr ----------------
__global__ __launch_bounds__(256) void k_graph(
    const float* __restrict__ gin, const float* __restrict__ h0,
    const float* __restrict__ c0, const double* __restrict__ wsd,
    float* __restrict__ gh)
{
  __shared__ double hdl[32*64];
  __shared__ double xld[32*64];
  __shared__ double ps[256], pq[256];
  const double* wihT = wsd + O_GWIHT;
  const double* whhT = wsd + O_GWHHT;
  const double* bd   = wsd + O_GB;
  const double* lng  = wsd + O_GLNG;
  const double* lnb  = wsd + O_GLNB;
  const int tid = threadIdx.x, lane = tid & 63;
  const int wv = __builtin_amdgcn_readfirstlane(tid >> 6);
  const int ub = wv*8;
  const int sb = blockIdx.x, ped0 = sb*64, ped = ped0 + lane;
  for (int idx = tid; idx < 2048; idx += 256){
    int f = idx>>6, p = idx&63;
    hdl[idx] = (double)h0[(ped0+p)*32 + f];
  }
  double c[8];
  #pragma unroll
  for (int j = 0; j < 8; ++j) c[j] = (double)c0[ped*32 + ub + j];

  for (int t = 0; t < T_OBS; ++t){
    __syncthreads();
    const float* gb = gin + (size_t)(t*NSC + sb)*2048;
    for (int idx = tid; idx < 2048; idx += 256) xld[idx] = (double)gb[idx];
    __syncthreads();
    double acc[32];
    #pragma unroll
    for (int j = 0; j < 8; ++j){
      #pragma unroll
      for (int g = 0; g < 4; ++g) acc[j*4+g] = bd[g*32 + ub + j];
    }
    for (int k = 0; k < 32; ++k){
      double xk = xld[k*64 + lane];
      double hk = hdl[k*64 + lane];
      const double* wi = wihT + k*128;
      const double* wh = whhT + k*128;
      #pragma unroll
      for (int j = 0; j < 8; ++j){
        #pragma unroll
        for (int g = 0; g < 4; ++g)
          acc[j*4+g] += wi[g*32 + ub + j]*xk + wh[g*32 + ub + j]*hk;
      }
    }
    double hp[8]; double s1 = 0, s2 = 0;
    #pragma unroll
    for (int j = 0; j < 8; ++j){
      double ig = fsig(acc[j*4+0]);
      double fg = fsig(acc[j*4+1]);
      double gg = ftanh(acc[j*4+2]);
      double og = fsig(acc[j*4+3]);
      c[j] = fg*c[j] + ig*gg;
      hp[j] = og*ftanh(c[j]);
      s1 += hp[j]; s2 += hp[j]*hp[j];
    }
    ps[wv*64+lane] = s1; pq[wv*64+lane] = s2;
    __syncthreads();
    double mu = (ps[lane]+ps[64+lane]+ps[128+lane]+ps[192+lane])*(1.0/32.0);
    double va = (pq[lane]+pq[64+lane]+pq[128+lane]+pq[192+lane])*(1.0/32.0) - mu*mu;
    double ri = fast_rsqrt(va + EPS);
    #pragma unroll
    for (int j = 0; j < 8; ++j){
      int u = ub + j;
      double hn = (hp[j]-mu)*ri*lng[u] + lnb[u];
      hdl[u*64 + lane] = hn;
      if (t == T_OBS-1) gh[ped*32 + u] = (float)hn;
    }
  }
}

// ---------------- K4: pred LSTM (2->80) + LN + head, 512 thr = 8 waves x 10 units ----------------
__global__ __launch_bounds__(512) void k_pred(
    const float* __restrict__ traj_hs, const float* __restrict__ gh,
    const float* __restrict__ zn, const float* __restrict__ obs,
    const double* __restrict__ wsd, float* __restrict__ outm)
{
  __shared__ double hd[80*64];
  __shared__ double ps[512], pq[512];
  __shared__ double po[512*2];
  const double* wT   = wsd + O_PWT;
  const double* wih  = wsd + O_PWIH;
  const double* bd   = wsd + O_PB;
  const double* lng  = wsd + O_PLNG;
  const double* lnb  = wsd + O_PLNB;
  const double* wout = wsd + O_PWOUT;
  const double* bout = wsd + O_PBOUT;
  const int tid = threadIdx.x, lane = tid & 63;
  const int wv = __builtin_amdgcn_readfirstlane(tid >> 6);
  const int ub = wv*10;
  const int scene = blockIdx.x, ped0 = scene*64, ped = ped0 + lane;

  for (int idx = tid; idx < 5120; idx += 512){
    int f = idx>>6, p = idx&63;
    float v;
    if (f < 32)      v = traj_hs[((size_t)7*NTOT + ped0 + p)*32 + f];
    else if (f < 64) v = gh[(ped0+p)*32 + (f-32)];
    else             v = zn[scene*16 + (f-64)];
    hd[idx] = (double)v;
  }
  double c[10];
  #pragma unroll
  for (int j = 0; j < 10; ++j) c[j] = 0.0;
  double x0 = (double)obs[((size_t)7*NTOT + ped)*2 + 0];
  double x1 = (double)obs[((size_t)7*NTOT + ped)*2 + 1];

  for (int t = 0; t < PRED_LEN; ++t){
    __syncthreads();
    double acc[40];
    #pragma unroll
    for (int j = 0; j < 10; ++j){
      #pragma unroll
      for (int g = 0; g < 4; ++g){
        int r = g*80 + ub + j;
        acc[j*4+g] = bd[r] + wih[r*2+0]*x0 + wih[r*2+1]*x1;
      }
    }
    for (int k = 0; k < 80; ++k){
      double hk = hd[k*64 + lane];
      const double* wr = wT + k*320 + ub;
      #pragma unroll
      for (int j = 0; j < 10; ++j){
        acc[j*4+0] += wr[j      ]*hk;
        acc[j*4+1] += wr[ 80 + j]*hk;
        acc[j*4+2] += wr[160 + j]*hk;
        acc[j*4+3] += wr[240 + j]*hk;
      }
    }
    double hp[10]; double s1 = 0, s2 = 0;
    #pragma unroll
    for (int j = 0; j < 10; ++j){
      double ig = fsig(acc[j*4+0]);
      double fg = fsig(acc[j*4+1]);
      double gg = ftanh(acc[j*4+2]);
      double og = fsig(acc[j*4+3]);
      c[j] = fg*c[j] + ig*gg;
      hp[j] = og*ftanh(c[j]);
      s1 += hp[j]; s2 += hp[j]*hp[j];
    }
    ps[wv*64+lane] = s1; pq[wv*64+lane] = s2;
    __syncthreads();
    double sa = 0, sq = 0;
    #pragma unroll
    for (int w = 0; w < 8; ++w){ sa += ps[w*64+lane]; sq += pq[w*64+lane]; }
    double mu = sa*(1.0/80.0);
    double va = sq*(1.0/80.0) - mu*mu;
    double ri = fast_rsqrt(va + EPS);
    double p0 = 0, p1 = 0;
    #pragma unroll
    for (int j = 0; j < 10; ++j){
      int u = ub + j;
      double hn = (hp[j]-mu)*ri*lng[u] + lnb[u];
      hd[u*64 + lane] = hn;
      p0 += hn*wout[u];
      p1 += hn*wout[80+u];
    }
    po[(wv*64+lane)*2+0] = p0; po[(wv*64+lane)*2+1] = p1;
    __syncthreads();
    double o0 = bout[0], o1 = bout[1];
    #pragma unroll
    for (int w = 0; w < 8; ++w){ o0 += po[(w*64+lane)*2+0]; o1 += po[(w*64+lane)*2+1]; }
    x0 = o0; x1 = o1;
    if (wv == 0){
      outm[((size_t)t*NTOT + ped)*2 + 0] = (float)x0;
      outm[((size_t)t*NTOT + ped)*2 + 1] = (float)x1;
    }
  }
}

// ---------------- K5: constant log_std / std outputs ----------------
__global__ void k_fill(const float* __restrict__ als, float* __restrict__ out) {
  const int M = PRED_LEN*NTOT*2;
  float l0 = als[0], l1 = als[1];
  float e0 = (float)exp((double)l0), e1 = (float)exp((double)l1);
  for (int i = blockIdx.x*256 + threadIdx.x; i < M; i += gridDim.x*256) {
    float lv = (i & 1) ? l1 : l0;
    float ev = (i & 1) ? e1 : e0;
    out[M + i]   = lv;
    out[2*M + i] = ev;
  }
}

extern "C" void kernel_launch(void* const* d_in, const int* in_sizes, int n_in,
                              void* d_out, int out_size, void* d_ws, size_t ws_size,
                              hipStream_t stream)
{
  const float* obs   = (const float*)d_in[0];
  const float* zn    = (const float*)d_in[2];
  const float* th0   = (const float*)d_in[3];
  const float* tc0   = (const float*)d_in[4];
  const float* gh0   = (const float*)d_in[5];
  const float* gc0   = (const float*)d_in[6];
  const float* gw0   = (const float*)d_in[7];
  const float* gas0  = (const float*)d_in[8];
  const float* gad0  = (const float*)d_in[9];
  const float* gb0   = (const float*)d_in[10];
  const float* gw1   = (const float*)d_in[11];
  const float* gas1  = (const float*)d_in[12];
  const float* gad1  = (const float*)d_in[13];
  const float* gb1   = (const float*)d_in[14];
  const float* twih  = (const float*)d_in[15];
  const float* twhh  = (const float*)d_in[16];
  const float* tbih  = (const float*)d_in[17];
  const float* tbhh  = (const float*)d_in[18];
  const float* gwih  = (const float*)d_in[19];
  const float* gwhh  = (const float*)d_in[20];
  const float* gbih  = (const float*)d_in[21];
  const float* gbhh  = (const float*)d_in[22];
  const float* glng  = (const float*)d_in[23];
  const float* glnb  = (const float*)d_in[24];
  const float* pwih  = (const float*)d_in[25];
  const float* pwhh  = (const float*)d_in[26];
  const float* pbih  = (const float*)d_in[27];
  const float* pbhh  = (const float*)d_in[28];
  const float* plng  = (const float*)d_in[29];
  const float* plnb  = (const float*)d_in[30];
  const float* poww  = (const float*)d_in[31];
  const float* pob   = (const float*)d_in[32];
  const float* als   = (const float*)d_in[33];

  float* out = (float*)d_out;
  double* wsd = (double*)d_ws;
  float* traj_hs = (float*)(wsd + D_TOTAL);         // [8][NTOT][32]
  float* gin     = traj_hs + (size_t)8*NTOT*32;     // [8][NSC][32][64]
  float* gh      = gin + (size_t)8*NTOT*32;         // [NTOT][32]

  k_prep<<<dim3(104), dim3(256), 0, stream>>>(
      pwhh, pwih, pbih, pbhh, plng, plnb, poww, pob,
      twih, twhh, tbih, tbhh, gwih, gwhh, gbih, gbhh, glng, glnb,
      gw0, gas0, gad0, gb0, gw1, gas1, gad1, gb1, wsd);
  k_traj<<<dim3(512), dim3(256), 0, stream>>>(obs, th0, tc0, wsd, traj_hs);
  k_gat<<<dim3(4096), dim3(256), 0, stream>>>(traj_hs, wsd, gin);
  k_graph<<<dim3(512), dim3(256), 0, stream>>>(gin, gh0, gc0, wsd, gh);
  k_pred<<<dim3(512), dim3(512), 0, stream>>>(traj_hs, gh, zn, obs, wsd, out);
  k_fill<<<dim3(1024), dim3(256), 0, stream>>>(als, out);
}

// Round 5
// 1407.866 us; speedup vs baseline: 1.3828x; 1.0364x over previous
//
#include <hip/hip_runtime.h>
#include <math.h>

#define T_OBS 8
#define PRED_LEN 12
#define NSC 512
#define NPED 64
#define NTOT (NSC*NPED)
#define EPS 1e-5

// ---- ws double-region offsets (in doubles) ----
#define O_PW2    0        // pred whh^T g-folded [80 k][320 r]
#define O_PWIH   25600    // pred wih [320][2]
#define O_PBD    26240    // pred bih+bhh+Cb [320]
#define O_PCW    26560    // Cw[r] [320]
#define O_PGW    26880    // gw0[80], gw1[80]
#define O_PSC    27040    // Cgw0, Cgw1, Cbw0+bout0, Cbw1+bout1
#define O_PINV   27048    // invg[80], b[80]
#define O_TWIH   27208    // traj wih [128][2]
#define O_TWHHT  27464    // traj whh^T [32 k][128 r]
#define O_TB     31560    // traj bih+bhh [128]
#define O_GWIHT  31688    // graph wih^T [32 k][128 r]
#define O_GW2    35784    // graph whh^T g-folded [32 k][128 r]
#define O_GBD    39880    // graph bih+bhh+gCb [128]
#define O_GCW    40008    // gCw[r] [128]
#define O_GLNG   40136
#define O_GLNB   40168
#define O_GINV   40200    // ginvg[32], gb[32]
#define O_W0     40264    // gat w0 [4][32][16]
#define O_A0S    42312
#define O_A0D    42376
#define O_B0     42440
#define O_W1     42456    // gat w1 [64][32]
#define O_A1S    44504
#define O_A1D    44536
#define O_B1     44568
#define D_TOTAL  44600

// ---------- fast fp64 math (validated bit-identical absmax R3/R4) ----------
__device__ __forceinline__ double fast_exp(double x){
  x = fmin(fmax(x, -708.0), 708.0);
  const double L2E  = 1.4426950408889634074;
  const double LN2H = 6.93147180369123816490e-01;
  const double LN2L = 1.90821492927058770002e-10;
  double t = x*L2E;
  double n = rint(t);
  int ni = (int)n;
  double r = __builtin_fma(-n, LN2H, x);
  r = __builtin_fma(-n, LN2L, r);
  double p = 2.08767569878681e-09;
  p = __builtin_fma(p, r, 2.505210838544172e-08);
  p = __builtin_fma(p, r, 2.755731922398589e-07);
  p = __builtin_fma(p, r, 2.755731922398589e-06);
  p = __builtin_fma(p, r, 2.480158730158730e-05);
  p = __builtin_fma(p, r, 1.984126984126984e-04);
  p = __builtin_fma(p, r, 1.388888888888889e-03);
  p = __builtin_fma(p, r, 8.333333333333333e-03);
  p = __builtin_fma(p, r, 4.166666666666667e-02);
  p = __builtin_fma(p, r, 1.666666666666667e-01);
  p = __builtin_fma(p, r, 0.5);
  p = __builtin_fma(p, r, 1.0);
  p = __builtin_fma(p, r, 1.0);
  double s = __hiloint2double((ni + 1023) << 20, 0);
  return p*s;
}
__device__ __forceinline__ double fast_rcp(double d){
#if __has_builtin(__builtin_amdgcn_rcp)
  double r = __builtin_amdgcn_rcp(d);
#else
  double r = 1.0/d;
#endif
  double e = __builtin_fma(-d, r, 1.0); r = __builtin_fma(r, e, r);
  e = __builtin_fma(-d, r, 1.0); r = __builtin_fma(r, e, r);
  e = __builtin_fma(-d, r, 1.0); r = __builtin_fma(r, e, r);
  return r;
}
__device__ __forceinline__ double fast_rsqrt(double d){
#if __has_builtin(__builtin_amdgcn_rsq)
  double r = __builtin_amdgcn_rsq(d);
#else
  double r = 1.0/sqrt(d);
#endif
  double hr = 0.5*d;
  r = r*__builtin_fma(-hr*r, r, 1.5);
  r = r*__builtin_fma(-hr*r, r, 1.5);
  r = r*__builtin_fma(-hr*r, r, 1.5);
  return r;
}
__device__ __forceinline__ double fsig(double x){
  double xc = fmin(fmax(x, -40.0), 40.0);
  return fast_rcp(1.0 + fast_exp(-xc));
}
__device__ __forceinline__ double ftanh(double x){
  double xc = fmin(fmax(x, -20.0), 20.0);
  return __builtin_fma(-2.0, fast_rcp(1.0 + fast_exp(2.0*xc)), 1.0);
}

// ---------------- prep: fp64 weights + LN-fold precomputes ----------------
__global__ void k_prep(
    const float* __restrict__ pwhh, const float* __restrict__ pwih,
    const float* __restrict__ pbih, const float* __restrict__ pbhh,
    const float* __restrict__ plng, const float* __restrict__ plnb,
    const float* __restrict__ pwout, const float* __restrict__ pbout,
    const float* __restrict__ twih, const float* __restrict__ twhh,
    const float* __restrict__ tbih, const float* __restrict__ tbhh,
    const float* __restrict__ gwih, const float* __restrict__ gwhh,
    const float* __restrict__ gbih, const float* __restrict__ gbhh,
    const float* __restrict__ glng, const float* __restrict__ glnb,
    const float* __restrict__ w0, const float* __restrict__ a0s,
    const float* __restrict__ a0d, const float* __restrict__ b0,
    const float* __restrict__ w1, const float* __restrict__ a1s,
    const float* __restrict__ a1d, const float* __restrict__ b1,
    double* __restrict__ wsd)
{
  int i = blockIdx.x*256 + threadIdx.x;
  // pred w2[k*320+r] = whh[r][k]*g[k]
  if (i < 25600){
    int k = i/320, r = i - k*320;
    wsd[O_PW2 + i] = (double)pwhh[r*80 + k] * (double)plng[k];
  }
  if (i < 640)  wsd[O_PWIH + i] = (double)pwih[i];
  if (i < 320){
    double s = 0, sb = 0;
    for (int k = 0; k < 80; ++k){
      double w = (double)pwhh[i*80 + k];
      s  += w*(double)plng[k];
      sb += w*(double)plnb[k];
    }
    wsd[O_PCW + i] = s;
    wsd[O_PBD + i] = (double)pbih[i] + (double)pbhh[i] + sb;
  }
  if (i < 160){
    if (i < 80) wsd[O_PGW + i] = (double)plng[i]*(double)pwout[i];
    else        wsd[O_PGW + i] = (double)plng[i-80]*(double)pwout[80 + (i-80)];
  }
  if (i < 4){
    double s = 0;
    if (i == 0){ for (int u = 0; u < 80; ++u) s += (double)plng[u]*(double)pwout[u]; }
    if (i == 1){ for (int u = 0; u < 80; ++u) s += (double)plng[u]*(double)pwout[80+u]; }
    if (i == 2){ for (int u = 0; u < 80; ++u) s += (double)plnb[u]*(double)pwout[u]; s += (double)pbout[0]; }
    if (i == 3){ for (int u = 0; u < 80; ++u) s += (double)plnb[u]*(double)pwout[80+u]; s += (double)pbout[1]; }
    wsd[O_PSC + i] = s;
  }
  if (i < 160){
    if (i < 80) wsd[O_PINV + i] = 1.0/(double)plng[i];
    else        wsd[O_PINV + i] = (double)plnb[i-80];
  }
  if (i < 256) wsd[O_TWIH + i] = (double)twih[i];
  if (i < 4096){
    int r = i>>5, k = i&31;
    wsd[O_TWHHT + k*128 + r] = (double)twhh[i];
    wsd[O_GWIHT + k*128 + r] = (double)gwih[i];
    wsd[O_GW2   + k*128 + r] = (double)gwhh[i]*(double)glng[k];
  }
  if (i < 128){
    wsd[O_TB + i] = (double)tbih[i] + (double)tbhh[i];
    double s = 0, sb = 0;
    for (int k = 0; k < 32; ++k){
      double w = (double)gwhh[i*32 + k];
      s  += w*(double)glng[k];
      sb += w*(double)glnb[k];
    }
    wsd[O_GCW + i] = s;
    wsd[O_GBD + i] = (double)gbih[i] + (double)gbhh[i] + sb;
  }
  if (i < 32){
    wsd[O_GLNG + i] = (double)glng[i]; wsd[O_GLNB + i] = (double)glnb[i];
    wsd[O_GINV + i] = 1.0/(double)glng[i];
    wsd[O_GINV + 32 + i] = (double)glnb[i];
    wsd[O_A1S + i] = (double)a1s[i]; wsd[O_A1D + i] = (double)a1d[i];
    wsd[O_B1 + i] = (double)b1[i];
  }
  if (i < 2048){ wsd[O_W0 + i] = (double)w0[i]; wsd[O_W1 + i] = (double)w1[i]; }
  if (i < 64){ wsd[O_A0S + i] = (double)a0s[i]; wsd[O_A0D + i] = (double)a0d[i]; }
  if (i < 16) wsd[O_B0 + i] = (double)b0[i];
}

// ---------------- K1: traj LSTM, double-buffered h, 1 barrier/step ----------------
__global__ __launch_bounds__(256) void k_traj(
    const float* __restrict__ obs, const float* __restrict__ h0,
    const float* __restrict__ c0, const double* __restrict__ wsd,
    float* __restrict__ traj_hs)
{
  __shared__ double hdl[2][2048];
  const double* wih  = wsd + O_TWIH;
  const double* whhT = wsd + O_TWHHT;
  const double* bd   = wsd + O_TB;
  const int tid = threadIdx.x, lane = tid & 63;
  const int wv = __builtin_amdgcn_readfirstlane(tid >> 6);
  const int ub = wv*8;
  const int ped0 = blockIdx.x*64, ped = ped0 + lane;
  for (int idx = tid; idx < 2048; idx += 256){
    int f = idx>>6, p = idx&63;
    hdl[0][idx] = (double)h0[(ped0+p)*32 + f];
  }
  double c[8];
  #pragma unroll
  for (int j = 0; j < 8; ++j) c[j] = (double)c0[ped*32 + ub + j];
  __syncthreads();

  for (int t = 0; t < T_OBS; ++t){
    const int p = t & 1;
    double x0 = (double)obs[((size_t)t*NTOT + ped)*2 + 0];
    double x1 = (double)obs[((size_t)t*NTOT + ped)*2 + 1];
    double acc[32];
    #pragma unroll
    for (int j = 0; j < 8; ++j){
      #pragma unroll
      for (int g = 0; g < 4; ++g){
        int r = g*32 + ub + j;
        acc[j*4+g] = bd[r] + wih[r*2+0]*x0 + wih[r*2+1]*x1;
      }
    }
    for (int k = 0; k < 32; ++k){
      double hk = hdl[p][k*64 + lane];
      const double* wh = whhT + k*128;
      #pragma unroll
      for (int j = 0; j < 8; ++j){
        #pragma unroll
        for (int g = 0; g < 4; ++g) acc[j*4+g] += wh[g*32 + ub + j]*hk;
      }
    }
    #pragma unroll
    for (int j = 0; j < 8; ++j){
      double ig = fsig(acc[j*4+0]);
      double fg = fsig(acc[j*4+1]);
      double gg = ftanh(acc[j*4+2]);
      double og = fsig(acc[j*4+3]);
      c[j] = fg*c[j] + ig*gg;
      double hn = og*ftanh(c[j]);
      hdl[p^1][(ub+j)*64 + lane] = hn;
      traj_hs[((size_t)t*NTOT + ped)*32 + ub + j] = (float)hn;
    }
    __syncthreads();
  }
}

// ---------------- K2: GAT encoder (no-max softmax, parallel L1) ----------------
__global__ __launch_bounds__(256) void k_gat(
    const float* __restrict__ ths, const double* __restrict__ wsd,
    float* __restrict__ gout)
{
  __shared__ float xA[64*65];
  __shared__ double hpB[64*68];
  __shared__ double as0[256], ad0[256];     // reused as pS/pD for L1 partials
  __shared__ double as1[64], ad1[64], zS[256], mn[64], rs[64];

  const double* w0  = wsd + O_W0;
  const double* a0s = wsd + O_A0S;
  const double* a0d = wsd + O_A0D;
  const double* b0  = wsd + O_B0;
  const double* w1  = wsd + O_W1;
  const double* a1s = wsd + O_A1S;
  const double* a1d = wsd + O_A1D;
  const double* b1  = wsd + O_B1;

  const int tid = threadIdx.x;
  const int sb = blockIdx.x >> 3, tb = blockIdx.x & 7;
  const int n = tid & 63;
  const int q = __builtin_amdgcn_readfirstlane(tid >> 6);

  const float* xin = ths + ((size_t)tb*NTOT + sb*64)*32;
  for (int idx = tid; idx < 2048; idx += 256)
    xA[(idx>>5)*65 + (idx&31)] = xin[idx];
  __syncthreads();
  if (tid < 32){
    double s1 = 0, s2 = 0;
    for (int p = 0; p < 64; ++p){ double v = xA[p*65+tid]; s1 += v; s2 += v*v; }
    double mu = s1*(1.0/64.0), va = s2*(1.0/64.0) - mu*mu;
    mn[tid] = mu; rs[tid] = fast_rsqrt(va + EPS);
  }
  __syncthreads();
  for (int idx = tid; idx < 2048; idx += 256){
    int p = idx>>5, f = idx&31;
    xA[p*65+f] = (float)(((double)xA[p*65+f] - mn[f])*rs[f]);
  }
  __syncthreads();
  { // hp0 + attn dots
    double acc[16];
    #pragma unroll
    for (int o = 0; o < 16; ++o) acc[o] = 0;
    for (int f = 0; f < 32; ++f){
      double xv = (double)xA[n*65+f];
      const double* wr = w0 + (q*32+f)*16;
      #pragma unroll
      for (int o = 0; o < 16; ++o) acc[o] += xv*wr[o];
    }
    double sa = 0, sd = 0;
    #pragma unroll
    for (int o = 0; o < 16; ++o){
      sa += acc[o]*a0s[q*16+o];
      sd += acc[o]*a0d[q*16+o];
      hpB[n*68 + q*16 + o] = acc[o];
    }
    as0[q*64+n] = sa; ad0[q*64+n] = sd;
  }
  __syncthreads();
  { // attn L0: exp (no max shift, safe fp64) + aggregate + bias + ELU
    double arow = as0[q*64+n];
    double num[16];
    #pragma unroll
    for (int o = 0; o < 16; ++o) num[o] = 0;
    double Z = 0;
    for (int m2 = 0; m2 < 64; ++m2){
      double e = arow + ad0[q*64+m2];
      double lr = e > 0 ? e : 0.2*e;
      double pv = fast_exp(lr);
      Z += pv;
      const double2* h2 = (const double2*)&hpB[m2*68 + q*16];
      #pragma unroll
      for (int o2 = 0; o2 < 8; ++o2){
        double2 v = h2[o2];
        num[o2*2+0] += pv*v.x; num[o2*2+1] += pv*v.y;
      }
    }
    double iZ = fast_rcp(Z);
    #pragma unroll
    for (int o = 0; o < 16; ++o){
      double y = num[o]*iZ + b0[o];
      xA[n*65 + q*16 + o] = (float)(y > 0 ? y : fast_exp(y)-1.0);
    }
  }
  __syncthreads();
  if (tid < 64){
    double s1 = 0, s2 = 0;
    for (int p = 0; p < 64; ++p){ double v = xA[p*65+tid]; s1 += v; s2 += v*v; }
    double mu = s1*(1.0/64.0), va = s2*(1.0/64.0) - mu*mu;
    mn[tid] = mu; rs[tid] = fast_rsqrt(va + EPS);
  }
  __syncthreads();
  for (int idx = tid; idx < 4096; idx += 256){
    int p = idx>>6, f = idx&63;
    xA[p*65+f] = (float)(((double)xA[p*65+f] - mn[f])*rs[f]);
  }
  __syncthreads();
  { // hp1
    double a8[8];
    #pragma unroll
    for (int j = 0; j < 8; ++j) a8[j] = 0;
    for (int f = 0; f < 64; ++f){
      double xv = (double)xA[n*65+f];
      const double* wr = w1 + f*32 + q*8;
      #pragma unroll
      for (int j = 0; j < 8; ++j) a8[j] += xv*wr[j];
    }
    #pragma unroll
    for (int j = 0; j < 8; ++j) hpB[n*68 + q*8 + j] = a8[j];
  }
  __syncthreads();
  { // as1/ad1 partials over o-slices (all 256 threads)
    double sa = 0, sd = 0;
    #pragma unroll
    for (int o = 0; o < 8; ++o){
      double v = hpB[n*68 + q*8 + o];
      sa += v*a1s[q*8+o]; sd += v*a1d[q*8+o];
    }
    as0[q*64+n] = sa; ad0[q*64+n] = sd;
  }
  __syncthreads();
  if (tid < 128){
    int n2 = tid & 63;
    if (tid < 64) as1[n2] = as0[n2]+as0[64+n2]+as0[128+n2]+as0[192+n2];
    else          ad1[n2] = ad0[n2]+ad0[64+n2]+ad0[128+n2]+ad0[192+n2];
  }
  __syncthreads();
  { // L1 softmax parallel: thread (n,q) handles 16 m's
    double arow = as1[n];
    double zp = 0;
    for (int m2 = q*16; m2 < q*16+16; ++m2){
      double e = arow + ad1[m2];
      double lr = e > 0 ? e : 0.2*e;
      double pv = fast_exp(lr);
      zp += pv;
      xA[n*65+m2] = (float)pv;
    }
    zS[q*64+n] = zp;
  }
  __syncthreads();
  { // aggregate L1, write gin as [t][scene][f][ped]
    double Z = zS[n]+zS[64+n]+zS[128+n]+zS[192+n];
    double iZ = fast_rcp(Z);
    double a8[8];
    #pragma unroll
    for (int j = 0; j < 8; ++j) a8[j] = 0;
    for (int m2 = 0; m2 < 64; ++m2){
      double av = (double)xA[n*65+m2];
      const double2* h2 = (const double2*)&hpB[m2*68 + q*8];
      double2 v0 = h2[0], v1 = h2[1], v2 = h2[2], v3 = h2[3];
      a8[0] += av*v0.x; a8[1] += av*v0.y; a8[2] += av*v1.x; a8[3] += av*v1.y;
      a8[4] += av*v2.x; a8[5] += av*v2.y; a8[6] += av*v3.x; a8[7] += av*v3.y;
    }
    float* go = gout + ((size_t)(tb*NSC + sb)*32)*64;
    #pragma unroll
    for (int j = 0; j < 8; ++j)
      go[(q*8+j)*64 + n] = (float)(a8[j]*iZ + b1[q*8+j]);
  }
}

// ---------------- K3: graph LSTM + folded LN, double-buffered, 1 barrier/step ----------------
__global__ __launch_bounds__(256) void k_graph(
    const float* __restrict__ gin, const float* __restrict__ h0,
    const float* __restrict__ c0, const double* __restrict__ wsd,
    float* __restrict__ gh)
{
  __shared__ double hdl[2][2048];
  __shared__ double xld[2][2048];
  __shared__ double ps[256], pq[256];
  const double* wihT = wsd + O_GWIHT;
  const double* w2   = wsd + O_GW2;
  const double* bdp  = wsd + O_GBD;
  const double* gCw  = wsd + O_GCW;
  const double* lng  = wsd + O_GLNG;
  const double* lnb  = wsd + O_GLNB;
  const double* ginv = wsd + O_GINV;
  const int tid = threadIdx.x, lane = tid & 63;
  const int wv = __builtin_amdgcn_readfirstlane(tid >> 6);
  const int ub = wv*8;
  const int sb = blockIdx.x, ped0 = sb*64, ped = ped0 + lane;
  for (int idx = tid; idx < 2048; idx += 256){
    int f = idx>>6, p = idx&63;
    // pre-LN representation: hp0 = (h0 - b)/g  (mu=0, ri=1)
    hdl[0][idx] = ((double)h0[(ped0+p)*32 + f] - ginv[32+f]) * ginv[f];
  }
  {
    const float* gb0p = gin + (size_t)(0*NSC + sb)*2048;
    for (int idx = tid; idx < 2048; idx += 256) xld[0][idx] = (double)gb0p[idx];
  }
  double c[8];
  #pragma unroll
  for (int j = 0; j < 8; ++j) c[j] = (double)c0[ped*32 + ub + j];
  double mu = 0.0, ri = 1.0;
  __syncthreads();

  for (int t = 0; t < T_OBS; ++t){
    const int p = t & 1;
    // stage next x-tile early (hides HBM/L2 latency under GEMV)
    if (t < T_OBS-1){
      const float* gbn = gin + (size_t)((t+1)*NSC + sb)*2048;
      for (int idx = tid; idx < 2048; idx += 256) xld[p^1][idx] = (double)gbn[idx];
    }
    double accX[32], accH[32];
    #pragma unroll
    for (int j4 = 0; j4 < 32; ++j4){ accX[j4] = 0; accH[j4] = 0; }
    for (int k = 0; k < 32; ++k){
      double xk = xld[p][k*64 + lane];
      double hk = hdl[p][k*64 + lane];
      const double* wi = wihT + k*128;
      const double* wh = w2   + k*128;
      #pragma unroll
      for (int j = 0; j < 8; ++j){
        #pragma unroll
        for (int g = 0; g < 4; ++g){
          accX[j*4+g] += wi[g*32 + ub + j]*xk;
          accH[j*4+g] += wh[g*32 + ub + j]*hk;
        }
      }
    }
    double hp[8]; double s1 = 0, s2 = 0;
    #pragma unroll
    for (int j = 0; j < 8; ++j){
      double pre[4];
      #pragma unroll
      for (int g = 0; g < 4; ++g){
        int r = g*32 + ub + j;
        pre[g] = bdp[r] + accX[j*4+g] + ri*__builtin_fma(-mu, gCw[r], accH[j*4+g]);
      }
      double ig = fsig(pre[0]);
      double fg = fsig(pre[1]);
      double gg = ftanh(pre[2]);
      double og = fsig(pre[3]);
      c[j] = fg*c[j] + ig*gg;
      hp[j] = og*ftanh(c[j]);
      s1 += hp[j]; s2 += hp[j]*hp[j];
      hdl[p^1][(ub+j)*64 + lane] = hp[j];
    }
    ps[wv*64+lane] = s1; pq[wv*64+lane] = s2;
    __syncthreads();
    double sa = ps[lane]+ps[64+lane]+ps[128+lane]+ps[192+lane];
    double sq = pq[lane]+pq[64+lane]+pq[128+lane]+pq[192+lane];
    mu = sa*(1.0/32.0);
    double va = sq*(1.0/32.0) - mu*mu;
    ri = fast_rsqrt(va + EPS);
    if (t == T_OBS-1){
      #pragma unroll
      for (int j = 0; j < 8; ++j){
        int u = ub + j;
        gh[ped*32 + u] = (float)((hp[j]-mu)*ri*lng[u] + lnb[u]);
      }
    }
  }
}

// ---------------- K4: pred LSTM, folded LN+head, 2 barriers/step ----------------
__global__ __launch_bounds__(512) void k_pred(
    const float* __restrict__ traj_hs, const float* __restrict__ gh,
    const float* __restrict__ zn, const float* __restrict__ obs,
    const double* __restrict__ wsd, const float* __restrict__ als,
    float* __restrict__ out)
{
  __shared__ double hd[5120];
  __shared__ double ps[512], pq[512], pw0[512], pw1[512];
  const double* w2   = wsd + O_PW2;
  const double* wih  = wsd + O_PWIH;
  const double* bdp  = wsd + O_PBD;
  const double* pCw  = wsd + O_PCW;
  const double* gw   = wsd + O_PGW;     // gw0[80], gw1[80]
  const double* psc  = wsd + O_PSC;
  const double* pinv = wsd + O_PINV;    // invg[80], b[80]
  const int tid = threadIdx.x, lane = tid & 63;
  const int wv = __builtin_amdgcn_readfirstlane(tid >> 6);
  const int ub = wv*10;
  const int scene = blockIdx.x, ped0 = scene*64, ped = ped0 + lane;

  for (int idx = tid; idx < 5120; idx += 512){
    int f = idx>>6, p = idx&63;
    float v;
    if (f < 32)      v = traj_hs[((size_t)7*NTOT + ped0 + p)*32 + f];
    else if (f < 64) v = gh[(ped0+p)*32 + (f-32)];
    else             v = zn[scene*16 + (f-64)];
    // pre-LN representation (mu=0, ri=1): hp0 = (h0 - b)/g
    hd[idx] = ((double)v - pinv[80+f]) * pinv[f];
  }
  double c[10];
  #pragma unroll
  for (int j = 0; j < 10; ++j) c[j] = 0.0;
  double x0 = (double)obs[((size_t)7*NTOT + ped)*2 + 0];
  double x1 = (double)obs[((size_t)7*NTOT + ped)*2 + 1];
  double mu = 0.0, ri = 1.0;
  const double Cgw0 = psc[0], Cgw1 = psc[1], Cbw0 = psc[2], Cbw1 = psc[3];
  __syncthreads();

  for (int t = 0; t < PRED_LEN; ++t){
    double accg[40];
    #pragma unroll
    for (int j4 = 0; j4 < 40; ++j4) accg[j4] = 0;
    for (int k = 0; k < 80; ++k){
      double hk = hd[k*64 + lane];
      const double* wr = w2 + k*320 + ub;
      #pragma unroll
      for (int j = 0; j < 10; ++j){
        accg[j*4+0] += wr[j      ]*hk;
        accg[j*4+1] += wr[ 80 + j]*hk;
        accg[j*4+2] += wr[160 + j]*hk;
        accg[j*4+3] += wr[240 + j]*hk;
      }
    }
    double hp[10]; double s1 = 0, s2 = 0, sw0 = 0, sw1 = 0;
    #pragma unroll
    for (int j = 0; j < 10; ++j){
      double pre[4];
      #pragma unroll
      for (int g = 0; g < 4; ++g){
        int r = g*80 + ub + j;
        pre[g] = bdp[r] + wih[r*2+0]*x0 + wih[r*2+1]*x1
               + ri*__builtin_fma(-mu, pCw[r], accg[j*4+g]);
      }
      double ig = fsig(pre[0]);
      double fg = fsig(pre[1]);
      double gg = ftanh(pre[2]);
      double og = fsig(pre[3]);
      c[j] = fg*c[j] + ig*gg;
      hp[j] = og*ftanh(c[j]);
      s1 += hp[j]; s2 += hp[j]*hp[j];
      sw0 += hp[j]*gw[ub+j]; sw1 += hp[j]*gw[80+ub+j];
    }
    __syncthreads();                 // R: all GEMV reads of hd done
    #pragma unroll
    for (int j = 0; j < 10; ++j) hd[(ub+j)*64 + lane] = hp[j];
    ps[wv*64+lane] = s1; pq[wv*64+lane] = s2;
    pw0[wv*64+lane] = sw0; pw1[wv*64+lane] = sw1;
    __syncthreads();                 // W: writes visible
    double sa = 0, sq = 0, t0 = 0, t1 = 0;
    #pragma unroll
    for (int w = 0; w < 8; ++w){
      sa += ps[w*64+lane]; sq += pq[w*64+lane];
      t0 += pw0[w*64+lane]; t1 += pw1[w*64+lane];
    }
    mu = sa*(1.0/80.0);
    double va = sq*(1.0/80.0) - mu*mu;
    ri = fast_rsqrt(va + EPS);
    x0 = ri*__builtin_fma(-mu, Cgw0, t0) + Cbw0;
    x1 = ri*__builtin_fma(-mu, Cgw1, t1) + Cbw1;
    if (wv == 0){
      out[((size_t)t*NTOT + ped)*2 + 0] = (float)x0;
      out[((size_t)t*NTOT + ped)*2 + 1] = (float)x1;
    }
  }
  // epilogue: constant log_std / std for this block's peds (replaces k_fill)
  {
    const int M = PRED_LEN*NTOT*2;
    float l0 = als[0], l1 = als[1];
    float e0 = (float)fast_exp((double)l0), e1 = (float)fast_exp((double)l1);
    for (int i = tid; i < PRED_LEN*64*2; i += 512){
      int t = i >> 7; int rem = i & 127; int p2 = rem >> 1; int ch = rem & 1;
      int gi = (t*NTOT + ped0 + p2)*2 + ch;
      out[M + gi]   = ch ? l1 : l0;
      out[2*M + gi] = ch ? e1 : e0;
    }
  }
}

extern "C" void kernel_launch(void* const* d_in, const int* in_sizes, int n_in,
                              void* d_out, int out_size, void* d_ws, size_t ws_size,
                              hipStream_t stream)
{
  const float* obs   = (const float*)d_in[0];
  const float* zn    = (const float*)d_in[2];
  const float* th0   = (const float*)d_in[3];
  const float* tc0   = (const float*)d_in[4];
  const float* gh0   = (const float*)d_in[5];
  const float* gc0   = (const float*)d_in[6];
  const float* gw0   = (const float*)d_in[7];
  const float* gas0  = (const float*)d_in[8];
  const float* gad0  = (const float*)d_in[9];
  const float* gb0   = (const float*)d_in[10];
  const float* gw1   = (const float*)d_in[11];
  const float* gas1  = (const float*)d_in[12];
  const float* gad1  = (const float*)d_in[13];
  const float* gb1   = (const float*)d_in[14];
  const float* twih  = (const float*)d_in[15];
  const float* twhh  = (const float*)d_in[16];
  const float* tbih  = (const float*)d_in[17];
  const float* tbhh  = (const float*)d_in[18];
  const float* gwih  = (const float*)d_in[19];
  const float* gwhh  = (const float*)d_in[20];
  const float* gbih  = (const float*)d_in[21];
  const float* gbhh  = (const float*)d_in[22];
  const float* glng  = (const float*)d_in[23];
  const float* glnb  = (const float*)d_in[24];
  const float* pwih  = (const float*)d_in[25];
  const float* pwhh  = (const float*)d_in[26];
  const float* pbih  = (const float*)d_in[27];
  const float* pbhh  = (const float*)d_in[28];
  const float* plng  = (const float*)d_in[29];
  const float* plnb  = (const float*)d_in[30];
  const float* poww  = (const float*)d_in[31];
  const float* pob   = (const float*)d_in[32];
  const float* als   = (const float*)d_in[33];

  float* out = (float*)d_out;
  double* wsd = (double*)d_ws;
  float* traj_hs = (float*)(wsd + D_TOTAL);         // [8][NTOT][32]
  float* gin     = traj_hs + (size_t)8*NTOT*32;     // [8][NSC][32][64]
  float* gh      = gin + (size_t)8*NTOT*32;         // [NTOT][32]

  k_prep<<<dim3(104), dim3(256), 0, stream>>>(
      pwhh, pwih, pbih, pbhh, plng, plnb, poww, pob,
      twih, twhh, tbih, tbhh, gwih, gwhh, gbih, gbhh, glng, glnb,
      gw0, gas0, gad0, gb0, gw1, gas1, gad1, gb1, wsd);
  k_traj<<<dim3(512), dim3(256), 0, stream>>>(obs, th0, tc0, wsd, traj_hs);
  k_gat<<<dim3(4096), dim3(256), 0, stream>>>(traj_hs, wsd, gin);
  k_graph<<<dim3(512), dim3(256), 0, stream>>>(gin, gh0, gc0, wsd, gh);
  k_pred<<<dim3(512), dim3(512), 0, stream>>>(traj_hs, gh, zn, obs, wsd, als, out);
}

// Round 6
// 1256.602 us; speedup vs baseline: 1.5492x; 1.1204x over previous
//
#include <hip/hip_runtime.h>
#include <math.h>

#define T_OBS 8
#define PRED_LEN 12
#define NSC 512
#define NPED 64
#define NTOT (NSC*NPED)
#define EPS 1e-5

// ---- ws double-region offsets (in doubles) ----
#define O_PWIH   25600    // pred wih [320][2]
#define O_PBD    26240    // pred bih+bhh+Cb [320]
#define O_PCW    26560    // Cw[r] [320]
#define O_PGW    26880    // gw0[80], gw1[80]
#define O_PSC    27040    // Cgw0, Cgw1, Cbw0+bout0, Cbw1+bout1
#define O_PINV   27048    // invg[80], b[80]
#define O_TWIH   27208    // traj wih [128][2]
#define O_TWHHT  27464    // traj whh^T [32 k][128 r]
#define O_TB     31560    // traj bih+bhh [128]
#define O_GWIHT  31688    // graph wih^T [32 k][128 r]
#define O_GW2    35784    // graph whh^T g-folded [32 k][128 r]
#define O_GBD    39880    // graph bih+bhh+gCb [128]
#define O_GCW    40008    // gCw[r] [128]
#define O_GLNG   40136
#define O_GLNB   40168
#define O_GINV   40200    // ginvg[32], gb[32]
#define O_W0     40264    // gat w0 [4][32][16]
#define O_A0S    42312
#define O_A0D    42376
#define O_B0     42440
#define O_W1     42456    // gat w1 [64][32]
#define O_A1S    44504
#define O_A1D    44536
#define O_B1     44568
#define D_TOTAL  44600
// float region (offsets in floats, from wsf = (float*)(wsd + D_TOTAL))
#define OF_PW2F  0        // pred whh^T g-folded fp32 [80 k][320 r]
#define F_TOTAL  25600

// ---------- fast fp64 math (validated bit-identical absmax R3/R4/R5) ----------
__device__ __forceinline__ double fast_exp(double x){
  x = fmin(fmax(x, -708.0), 708.0);
  const double L2E  = 1.4426950408889634074;
  const double LN2H = 6.93147180369123816490e-01;
  const double LN2L = 1.90821492927058770002e-10;
  double t = x*L2E;
  double n = rint(t);
  int ni = (int)n;
  double r = __builtin_fma(-n, LN2H, x);
  r = __builtin_fma(-n, LN2L, r);
  double p = 2.08767569878681e-09;
  p = __builtin_fma(p, r, 2.505210838544172e-08);
  p = __builtin_fma(p, r, 2.755731922398589e-07);
  p = __builtin_fma(p, r, 2.755731922398589e-06);
  p = __builtin_fma(p, r, 2.480158730158730e-05);
  p = __builtin_fma(p, r, 1.984126984126984e-04);
  p = __builtin_fma(p, r, 1.388888888888889e-03);
  p = __builtin_fma(p, r, 8.333333333333333e-03);
  p = __builtin_fma(p, r, 4.166666666666667e-02);
  p = __builtin_fma(p, r, 1.666666666666667e-01);
  p = __builtin_fma(p, r, 0.5);
  p = __builtin_fma(p, r, 1.0);
  p = __builtin_fma(p, r, 1.0);
  double s = __hiloint2double((ni + 1023) << 20, 0);
  return p*s;
}
__device__ __forceinline__ double fast_rcp(double d){
#if __has_builtin(__builtin_amdgcn_rcp)
  double r = __builtin_amdgcn_rcp(d);
#else
  double r = 1.0/d;
#endif
  double e = __builtin_fma(-d, r, 1.0); r = __builtin_fma(r, e, r);
  e = __builtin_fma(-d, r, 1.0); r = __builtin_fma(r, e, r);
  e = __builtin_fma(-d, r, 1.0); r = __builtin_fma(r, e, r);
  return r;
}
__device__ __forceinline__ double fast_rsqrt(double d){
#if __has_builtin(__builtin_amdgcn_rsq)
  double r = __builtin_amdgcn_rsq(d);
#else
  double r = 1.0/sqrt(d);
#endif
  double hr = 0.5*d;
  r = r*__builtin_fma(-hr*r, r, 1.5);
  r = r*__builtin_fma(-hr*r, r, 1.5);
  r = r*__builtin_fma(-hr*r, r, 1.5);
  return r;
}
__device__ __forceinline__ double fsig(double x){
  double xc = fmin(fmax(x, -40.0), 40.0);
  return fast_rcp(1.0 + fast_exp(-xc));
}
__device__ __forceinline__ double ftanh(double x){
  double xc = fmin(fmax(x, -20.0), 20.0);
  return __builtin_fma(-2.0, fast_rcp(1.0 + fast_exp(2.0*xc)), 1.0);
}

// ---------------- prep ----------------
__global__ void k_prep(
    const float* __restrict__ pwhh, const float* __restrict__ pwih,
    const float* __restrict__ pbih, const float* __restrict__ pbhh,
    const float* __restrict__ plng, const float* __restrict__ plnb,
    const float* __restrict__ pwout, const float* __restrict__ pbout,
    const float* __restrict__ twih, const float* __restrict__ twhh,
    const float* __restrict__ tbih, const float* __restrict__ tbhh,
    const float* __restrict__ gwih, const float* __restrict__ gwhh,
    const float* __restrict__ gbih, const float* __restrict__ gbhh,
    const float* __restrict__ glng, const float* __restrict__ glnb,
    const float* __restrict__ w0, const float* __restrict__ a0s,
    const float* __restrict__ a0d, const float* __restrict__ b0,
    const float* __restrict__ w1, const float* __restrict__ a1s,
    const float* __restrict__ a1d, const float* __restrict__ b1,
    double* __restrict__ wsd, float* __restrict__ wsf)
{
  int i = blockIdx.x*256 + threadIdx.x;
  // pred w2f[k*320+r] = whh[r][k]*g[k]  (fp32)
  if (i < 25600){
    int k = i/320, r = i - k*320;
    wsf[OF_PW2F + i] = (float)((double)pwhh[r*80 + k] * (double)plng[k]);
  }
  if (i < 640)  wsd[O_PWIH + i] = (double)pwih[i];
  if (i < 320){
    double s = 0, sb = 0;
    for (int k = 0; k < 80; ++k){
      double w = (double)pwhh[i*80 + k];
      s  += w*(double)plng[k];
      sb += w*(double)plnb[k];
    }
    wsd[O_PCW + i] = s;
    wsd[O_PBD + i] = (double)pbih[i] + (double)pbhh[i] + sb;
  }
  if (i < 160){
    if (i < 80) wsd[O_PGW + i] = (double)plng[i]*(double)pwout[i];
    else        wsd[O_PGW + i] = (double)plng[i-80]*(double)pwout[80 + (i-80)];
  }
  if (i < 4){
    double s = 0;
    if (i == 0){ for (int u = 0; u < 80; ++u) s += (double)plng[u]*(double)pwout[u]; }
    if (i == 1){ for (int u = 0; u < 80; ++u) s += (double)plng[u]*(double)pwout[80+u]; }
    if (i == 2){ for (int u = 0; u < 80; ++u) s += (double)plnb[u]*(double)pwout[u]; s += (double)pbout[0]; }
    if (i == 3){ for (int u = 0; u < 80; ++u) s += (double)plnb[u]*(double)pwout[80+u]; s += (double)pbout[1]; }
    wsd[O_PSC + i] = s;
  }
  if (i < 160){
    if (i < 80) wsd[O_PINV + i] = 1.0/(double)plng[i];
    else        wsd[O_PINV + i] = (double)plnb[i-80];
  }
  if (i < 256) wsd[O_TWIH + i] = (double)twih[i];
  if (i < 4096){
    int r = i>>5, k = i&31;
    wsd[O_TWHHT + k*128 + r] = (double)twhh[i];
    wsd[O_GWIHT + k*128 + r] = (double)gwih[i];
    wsd[O_GW2   + k*128 + r] = (double)gwhh[i]*(double)glng[k];
  }
  if (i < 128){
    wsd[O_TB + i] = (double)tbih[i] + (double)tbhh[i];
    double s = 0, sb = 0;
    for (int k = 0; k < 32; ++k){
      double w = (double)gwhh[i*32 + k];
      s  += w*(double)glng[k];
      sb += w*(double)glnb[k];
    }
    wsd[O_GCW + i] = s;
    wsd[O_GBD + i] = (double)gbih[i] + (double)gbhh[i] + sb;
  }
  if (i < 32){
    wsd[O_GLNG + i] = (double)glng[i]; wsd[O_GLNB + i] = (double)glnb[i];
    wsd[O_GINV + i] = 1.0/(double)glng[i];
    wsd[O_GINV + 32 + i] = (double)glnb[i];
    wsd[O_A1S + i] = (double)a1s[i]; wsd[O_A1D + i] = (double)a1d[i];
    wsd[O_B1 + i] = (double)b1[i];
  }
  if (i < 2048){ wsd[O_W0 + i] = (double)w0[i]; wsd[O_W1 + i] = (double)w1[i]; }
  if (i < 64){ wsd[O_A0S + i] = (double)a0s[i]; wsd[O_A0D + i] = (double)a0d[i]; }
  if (i < 16) wsd[O_B0 + i] = (double)b0[i];
}

// ---------------- K1: traj LSTM (unchanged from R5) ----------------
__global__ __launch_bounds__(256) void k_traj(
    const float* __restrict__ obs, const float* __restrict__ h0,
    const float* __restrict__ c0, const double* __restrict__ wsd,
    float* __restrict__ traj_hs)
{
  __shared__ double hdl[2][2048];
  const double* wih  = wsd + O_TWIH;
  const double* whhT = wsd + O_TWHHT;
  const double* bd   = wsd + O_TB;
  const int tid = threadIdx.x, lane = tid & 63;
  const int wv = __builtin_amdgcn_readfirstlane(tid >> 6);
  const int ub = wv*8;
  const int ped0 = blockIdx.x*64, ped = ped0 + lane;
  for (int idx = tid; idx < 2048; idx += 256){
    int f = idx>>6, p = idx&63;
    hdl[0][idx] = (double)h0[(ped0+p)*32 + f];
  }
  double c[8];
  #pragma unroll
  for (int j = 0; j < 8; ++j) c[j] = (double)c0[ped*32 + ub + j];
  __syncthreads();

  for (int t = 0; t < T_OBS; ++t){
    const int p = t & 1;
    double x0 = (double)obs[((size_t)t*NTOT + ped)*2 + 0];
    double x1 = (double)obs[((size_t)t*NTOT + ped)*2 + 1];
    double acc[32];
    #pragma unroll
    for (int j = 0; j < 8; ++j){
      #pragma unroll
      for (int g = 0; g < 4; ++g){
        int r = g*32 + ub + j;
        acc[j*4+g] = bd[r] + wih[r*2+0]*x0 + wih[r*2+1]*x1;
      }
    }
    for (int k = 0; k < 32; ++k){
      double hk = hdl[p][k*64 + lane];
      const double* wh = whhT + k*128;
      #pragma unroll
      for (int j = 0; j < 8; ++j){
        #pragma unroll
        for (int g = 0; g < 4; ++g) acc[j*4+g] += wh[g*32 + ub + j]*hk;
      }
    }
    #pragma unroll
    for (int j = 0; j < 8; ++j){
      double ig = fsig(acc[j*4+0]);
      double fg = fsig(acc[j*4+1]);
      double gg = ftanh(acc[j*4+2]);
      double og = fsig(acc[j*4+3]);
      c[j] = fg*c[j] + ig*gg;
      double hn = og*ftanh(c[j]);
      hdl[p^1][(ub+j)*64 + lane] = hn;
      traj_hs[((size_t)t*NTOT + ped)*32 + ub + j] = (float)hn;
    }
    __syncthreads();
  }
}

// ---------------- K2: GAT encoder — fp64 GEMVs, fp32 attention/softmax ----------------
__global__ __launch_bounds__(256) void k_gat(
    const float* __restrict__ ths, const double* __restrict__ wsd,
    float* __restrict__ gout)
{
  __shared__ float xA[64*65];
  __shared__ float hpB[64*68];               // fp32 h-prime storage
  __shared__ double as0[256], ad0[256];
  __shared__ double as1[64], ad1[64], mn[64], rs[64];
  __shared__ float zS[256];

  const double* w0  = wsd + O_W0;
  const double* a0s = wsd + O_A0S;
  const double* a0d = wsd + O_A0D;
  const double* b0  = wsd + O_B0;
  const double* w1  = wsd + O_W1;
  const double* a1s = wsd + O_A1S;
  const double* a1d = wsd + O_A1D;
  const double* b1  = wsd + O_B1;

  const int tid = threadIdx.x;
  const int sb = blockIdx.x >> 3, tb = blockIdx.x & 7;
  const int n = tid & 63;
  const int q = __builtin_amdgcn_readfirstlane(tid >> 6);

  const float* xin = ths + ((size_t)tb*NTOT + sb*64)*32;
  for (int idx = tid; idx < 2048; idx += 256)
    xA[(idx>>5)*65 + (idx&31)] = xin[idx];
  __syncthreads();
  if (tid < 32){
    double s1 = 0, s2 = 0;
    for (int p = 0; p < 64; ++p){ double v = xA[p*65+tid]; s1 += v; s2 += v*v; }
    double mu = s1*(1.0/64.0), va = s2*(1.0/64.0) - mu*mu;
    mn[tid] = mu; rs[tid] = fast_rsqrt(va + EPS);
  }
  __syncthreads();
  for (int idx = tid; idx < 2048; idx += 256){
    int p = idx>>5, f = idx&31;
    xA[p*65+f] = (float)(((double)xA[p*65+f] - mn[f])*rs[f]);
  }
  __syncthreads();
  { // hp0 (fp64) + attn dots (fp64), store hp0 fp32
    double acc[16];
    #pragma unroll
    for (int o = 0; o < 16; ++o) acc[o] = 0;
    for (int f = 0; f < 32; ++f){
      double xv = (double)xA[n*65+f];
      const double* wr = w0 + (q*32+f)*16;
      #pragma unroll
      for (int o = 0; o < 16; ++o) acc[o] += xv*wr[o];
    }
    double sa = 0, sd = 0;
    #pragma unroll
    for (int o = 0; o < 16; ++o){
      sa += acc[o]*a0s[q*16+o];
      sd += acc[o]*a0d[q*16+o];
      hpB[n*68 + q*16 + o] = (float)acc[o];
    }
    as0[q*64+n] = sa; ad0[q*64+n] = sd;
  }
  __syncthreads();
  { // attn L0: fp32 exp (const shift cancels), fp32 aggregate, ELU fp32
    float arow = (float)as0[q*64+n];
    float num[16];
    #pragma unroll
    for (int o = 0; o < 16; ++o) num[o] = 0.f;
    float Z = 0.f;
    for (int m2 = 0; m2 < 64; ++m2){
      float e = arow + (float)ad0[q*64+m2];
      float lr = e > 0.f ? e : 0.2f*e;
      float pv = __expf(lr - 30.0f);
      Z += pv;
      const float4* h4 = (const float4*)&hpB[m2*68 + q*16];
      #pragma unroll
      for (int o4 = 0; o4 < 4; ++o4){
        float4 v = h4[o4];
        num[o4*4+0] += pv*v.x; num[o4*4+1] += pv*v.y;
        num[o4*4+2] += pv*v.z; num[o4*4+3] += pv*v.w;
      }
    }
    float iZ = 1.0f/Z;
    #pragma unroll
    for (int o = 0; o < 16; ++o){
      float y = num[o]*iZ + (float)b0[o];
      xA[n*65 + q*16 + o] = y > 0.f ? y : __expf(y)-1.0f;
    }
  }
  __syncthreads();
  if (tid < 64){
    double s1 = 0, s2 = 0;
    for (int p = 0; p < 64; ++p){ double v = xA[p*65+tid]; s1 += v; s2 += v*v; }
    double mu = s1*(1.0/64.0), va = s2*(1.0/64.0) - mu*mu;
    mn[tid] = mu; rs[tid] = fast_rsqrt(va + EPS);
  }
  __syncthreads();
  for (int idx = tid; idx < 4096; idx += 256){
    int p = idx>>6, f = idx&63;
    xA[p*65+f] = (float)(((double)xA[p*65+f] - mn[f])*rs[f]);
  }
  __syncthreads();
  { // hp1 (fp64 compute, fp32 store)
    double a8[8];
    #pragma unroll
    for (int j = 0; j < 8; ++j) a8[j] = 0;
    for (int f = 0; f < 64; ++f){
      double xv = (double)xA[n*65+f];
      const double* wr = w1 + f*32 + q*8;
      #pragma unroll
      for (int j = 0; j < 8; ++j) a8[j] += xv*wr[j];
    }
    #pragma unroll
    for (int j = 0; j < 8; ++j) hpB[n*68 + q*8 + j] = (float)a8[j];
  }
  __syncthreads();
  { // as1/ad1 partials
    double sa = 0, sd = 0;
    #pragma unroll
    for (int o = 0; o < 8; ++o){
      double v = (double)hpB[n*68 + q*8 + o];
      sa += v*a1s[q*8+o]; sd += v*a1d[q*8+o];
    }
    as0[q*64+n] = sa; ad0[q*64+n] = sd;
  }
  __syncthreads();
  if (tid < 128){
    int n2 = tid & 63;
    if (tid < 64) as1[n2] = as0[n2]+as0[64+n2]+as0[128+n2]+as0[192+n2];
    else          ad1[n2] = ad0[n2]+ad0[64+n2]+ad0[128+n2]+ad0[192+n2];
  }
  __syncthreads();
  { // L1 softmax probs fp32: thread (n,q) 16 m's
    float arow = (float)as1[n];
    float zp = 0.f;
    for (int m2 = q*16; m2 < q*16+16; ++m2){
      float e = arow + (float)ad1[m2];
      float lr = e > 0.f ? e : 0.2f*e;
      float pv = __expf(lr - 30.0f);
      zp += pv;
      xA[n*65+m2] = pv;
    }
    zS[q*64+n] = zp;
  }
  __syncthreads();
  { // aggregate L1 fp32, write gin as [t][scene][f][ped]
    float Z = zS[n]+zS[64+n]+zS[128+n]+zS[192+n];
    float iZ = 1.0f/Z;
    float a8[8];
    #pragma unroll
    for (int j = 0; j < 8; ++j) a8[j] = 0.f;
    for (int m2 = 0; m2 < 64; ++m2){
      float av = xA[n*65+m2];
      const float4* h4 = (const float4*)&hpB[m2*68 + q*8];
      float4 v0 = h4[0], v1 = h4[1];
      a8[0] += av*v0.x; a8[1] += av*v0.y; a8[2] += av*v0.z; a8[3] += av*v0.w;
      a8[4] += av*v1.x; a8[5] += av*v1.y; a8[6] += av*v1.z; a8[7] += av*v1.w;
    }
    float* go = gout + ((size_t)(tb*NSC + sb)*32)*64;
    #pragma unroll
    for (int j = 0; j < 8; ++j)
      go[(q*8+j)*64 + n] = a8[j]*iZ + (float)b1[q*8+j];
  }
}

// ---------------- K3: graph LSTM + folded LN (unchanged from R5) ----------------
__global__ __launch_bounds__(256) void k_graph(
    const float* __restrict__ gin, const float* __restrict__ h0,
    const float* __restrict__ c0, const double* __restrict__ wsd,
    float* __restrict__ gh)
{
  __shared__ double hdl[2][2048];
  __shared__ double xld[2][2048];
  __shared__ double ps[256], pq[256];
  const double* wihT = wsd + O_GWIHT;
  const double* w2   = wsd + O_GW2;
  const double* bdp  = wsd + O_GBD;
  const double* gCw  = wsd + O_GCW;
  const double* lng  = wsd + O_GLNG;
  const double* lnb  = wsd + O_GLNB;
  const double* ginv = wsd + O_GINV;
  const int tid = threadIdx.x, lane = tid & 63;
  const int wv = __builtin_amdgcn_readfirstlane(tid >> 6);
  const int ub = wv*8;
  const int sb = blockIdx.x, ped0 = sb*64, ped = ped0 + lane;
  for (int idx = tid; idx < 2048; idx += 256){
    int f = idx>>6, p = idx&63;
    hdl[0][idx] = ((double)h0[(ped0+p)*32 + f] - ginv[32+f]) * ginv[f];
  }
  {
    const float* gb0p = gin + (size_t)(0*NSC + sb)*2048;
    for (int idx = tid; idx < 2048; idx += 256) xld[0][idx] = (double)gb0p[idx];
  }
  double c[8];
  #pragma unroll
  for (int j = 0; j < 8; ++j) c[j] = (double)c0[ped*32 + ub + j];
  double mu = 0.0, ri = 1.0;
  __syncthreads();

  for (int t = 0; t < T_OBS; ++t){
    const int p = t & 1;
    if (t < T_OBS-1){
      const float* gbn = gin + (size_t)((t+1)*NSC + sb)*2048;
      for (int idx = tid; idx < 2048; idx += 256) xld[p^1][idx] = (double)gbn[idx];
    }
    double accX[32], accH[32];
    #pragma unroll
    for (int j4 = 0; j4 < 32; ++j4){ accX[j4] = 0; accH[j4] = 0; }
    for (int k = 0; k < 32; ++k){
      double xk = xld[p][k*64 + lane];
      double hk = hdl[p][k*64 + lane];
      const double* wi = wihT + k*128;
      const double* wh = w2   + k*128;
      #pragma unroll
      for (int j = 0; j < 8; ++j){
        #pragma unroll
        for (int g = 0; g < 4; ++g){
          accX[j*4+g] += wi[g*32 + ub + j]*xk;
          accH[j*4+g] += wh[g*32 + ub + j]*hk;
        }
      }
    }
    double hp[8]; double s1 = 0, s2 = 0;
    #pragma unroll
    for (int j = 0; j < 8; ++j){
      double pre[4];
      #pragma unroll
      for (int g = 0; g < 4; ++g){
        int r = g*32 + ub + j;
        pre[g] = bdp[r] + accX[j*4+g] + ri*__builtin_fma(-mu, gCw[r], accH[j*4+g]);
      }
      double ig = fsig(pre[0]);
      double fg = fsig(pre[1]);
      double gg = ftanh(pre[2]);
      double og = fsig(pre[3]);
      c[j] = fg*c[j] + ig*gg;
      hp[j] = og*ftanh(c[j]);
      s1 += hp[j]; s2 += hp[j]*hp[j];
      hdl[p^1][(ub+j)*64 + lane] = hp[j];
    }
    ps[wv*64+lane] = s1; pq[wv*64+lane] = s2;
    __syncthreads();
    double sa = ps[lane]+ps[64+lane]+ps[128+lane]+ps[192+lane];
    double sq = pq[lane]+pq[64+lane]+pq[128+lane]+pq[192+lane];
    mu = sa*(1.0/32.0);
    double va = sq*(1.0/32.0) - mu*mu;
    ri = fast_rsqrt(va + EPS);
    if (t == T_OBS-1){
      #pragma unroll
      for (int j = 0; j < 8; ++j){
        int u = ub + j;
        gh[ped*32 + u] = (float)((hp[j]-mu)*ri*lng[u] + lnb[u]);
      }
    }
  }
}

// ---------------- K4: pred LSTM — fp32 h-GEMV, fp64 gates/LN/state ----------------
__global__ __launch_bounds__(512) void k_pred(
    const float* __restrict__ traj_hs, const float* __restrict__ gh,
    const float* __restrict__ zn, const float* __restrict__ obs,
    const double* __restrict__ wsd, const float* __restrict__ w2f,
    const float* __restrict__ als, float* __restrict__ out)
{
  __shared__ float hd[5120];                  // h (pre-LN rep) fp32
  __shared__ double ps[512], pq[512];
  __shared__ float pw0[512], pw1[512];
  const double* wih  = wsd + O_PWIH;
  const double* bdp  = wsd + O_PBD;
  const double* pCw  = wsd + O_PCW;
  const double* gw   = wsd + O_PGW;
  const double* psc  = wsd + O_PSC;
  const double* pinv = wsd + O_PINV;
  const int tid = threadIdx.x, lane = tid & 63;
  const int wv = __builtin_amdgcn_readfirstlane(tid >> 6);
  const int ub = wv*10;
  const int scene = blockIdx.x, ped0 = scene*64, ped = ped0 + lane;

  for (int idx = tid; idx < 5120; idx += 512){
    int f = idx>>6, p = idx&63;
    float v;
    if (f < 32)      v = traj_hs[((size_t)7*NTOT + ped0 + p)*32 + f];
    else if (f < 64) v = gh[(ped0+p)*32 + (f-32)];
    else             v = zn[scene*16 + (f-64)];
    hd[idx] = (float)(((double)v - pinv[80+f]) * pinv[f]);
  }
  // epilogue-first: constant log_std / std outputs (independent of the loop)
  {
    const int M = PRED_LEN*NTOT*2;
    float l0 = als[0], l1 = als[1];
    float e0 = (float)fast_exp((double)l0), e1 = (float)fast_exp((double)l1);
    for (int i = tid; i < PRED_LEN*64*2; i += 512){
      int t = i >> 7; int rem = i & 127; int p2 = rem >> 1; int ch = rem & 1;
      int gi = (t*NTOT + ped0 + p2)*2 + ch;
      out[M + gi]   = ch ? l1 : l0;
      out[2*M + gi] = ch ? e1 : e0;
    }
  }
  double c[10];
  #pragma unroll
  for (int j = 0; j < 10; ++j) c[j] = 0.0;
  double x0 = (double)obs[((size_t)7*NTOT + ped)*2 + 0];
  double x1 = (double)obs[((size_t)7*NTOT + ped)*2 + 1];
  double mu = 0.0, ri = 1.0, invri = 1.0;
  const double Cgw0 = psc[0], Cgw1 = psc[1], Cbw0 = psc[2], Cbw1 = psc[3];
  __syncthreads();

  for (int t = 0; t < PRED_LEN; ++t){
    // hoisted init (scaled by invri so final pre = ri*acc): fp32 accumulator
    float accg[40];
    #pragma unroll
    for (int j = 0; j < 10; ++j){
      #pragma unroll
      for (int g = 0; g < 4; ++g){
        int r = g*80 + ub + j;
        accg[j*4+g] = (float)(__builtin_fma(bdp[r] + wih[r*2+0]*x0 + wih[r*2+1]*x1,
                                            invri, -mu*pCw[r]));
      }
    }
    // fp32 GEMV over h (2x rate): pre = ri * (init/ri - mu*Cw + sum w2*h)
    for (int k = 0; k < 80; ++k){
      float hk = hd[k*64 + lane];
      const float* wr = w2f + k*320 + ub;
      #pragma unroll
      for (int j = 0; j < 10; ++j){
        accg[j*4+0] += wr[j      ]*hk;
        accg[j*4+1] += wr[ 80 + j]*hk;
        accg[j*4+2] += wr[160 + j]*hk;
        accg[j*4+3] += wr[240 + j]*hk;
      }
    }
    double hp[10]; double s1 = 0, s2 = 0, sw0 = 0, sw1 = 0;
    #pragma unroll
    for (int j = 0; j < 10; ++j){
      double ig = fsig(ri*(double)accg[j*4+0]);
      double fg = fsig(ri*(double)accg[j*4+1]);
      double gg = ftanh(ri*(double)accg[j*4+2]);
      double og = fsig(ri*(double)accg[j*4+3]);
      c[j] = fg*c[j] + ig*gg;
      hp[j] = og*ftanh(c[j]);
      s1 += hp[j]; s2 += hp[j]*hp[j];
      sw0 += hp[j]*gw[ub+j]; sw1 += hp[j]*gw[80+ub+j];
    }
    __syncthreads();                 // all GEMV reads of hd done
    #pragma unroll
    for (int j = 0; j < 10; ++j) hd[(ub+j)*64 + lane] = (float)hp[j];
    ps[wv*64+lane] = s1; pq[wv*64+lane] = s2;
    pw0[wv*64+lane] = (float)sw0; pw1[wv*64+lane] = (float)sw1;
    __syncthreads();                 // writes visible
    double sa = 0, sq = 0, t0 = 0, t1 = 0;
    #pragma unroll
    for (int w = 0; w < 8; ++w){
      sa += ps[w*64+lane]; sq += pq[w*64+lane];
      t0 += (double)pw0[w*64+lane]; t1 += (double)pw1[w*64+lane];
    }
    mu = sa*(1.0/80.0);
    double va = sq*(1.0/80.0) - mu*mu;
    ri = fast_rsqrt(va + EPS);
    invri = (va + EPS)*ri;           // = sqrt(va+EPS) = 1/ri
    x0 = ri*__builtin_fma(-mu, Cgw0, t0) + Cbw0;
    x1 = ri*__builtin_fma(-mu, Cgw1, t1) + Cbw1;
    if (wv == 0){
      out[((size_t)t*NTOT + ped)*2 + 0] = (float)x0;
      out[((size_t)t*NTOT + ped)*2 + 1] = (float)x1;
    }
  }
}

extern "C" void kernel_launch(void* const* d_in, const int* in_sizes, int n_in,
                              void* d_out, int out_size, void* d_ws, size_t ws_size,
                              hipStream_t stream)
{
  const float* obs   = (const float*)d_in[0];
  const float* zn    = (const float*)d_in[2];
  const float* th0   = (const float*)d_in[3];
  const float* tc0   = (const float*)d_in[4];
  const float* gh0   = (const float*)d_in[5];
  const float* gc0   = (const float*)d_in[6];
  const float* gw0   = (const float*)d_in[7];
  const float* gas0  = (const float*)d_in[8];
  const float* gad0  = (const float*)d_in[9];
  const float* gb0   = (const float*)d_in[10];
  const float* gw1   = (const float*)d_in[11];
  const float* gas1  = (const float*)d_in[12];
  const float* gad1  = (const float*)d_in[13];
  const float* gb1   = (const float*)d_in[14];
  const float* twih  = (const float*)d_in[15];
  const float* twhh  = (const float*)d_in[16];
  const float* tbih  = (const float*)d_in[17];
  const float* tbhh  = (const float*)d_in[18];
  const float* gwih  = (const float*)d_in[19];
  const float* gwhh  = (const float*)d_in[20];
  const float* gbih  = (const float*)d_in[21];
  const float* gbhh  = (const float*)d_in[22];
  const float* glng  = (const float*)d_in[23];
  const float* glnb  = (const float*)d_in[24];
  const float* pwih  = (const float*)d_in[25];
  const float* pwhh  = (const float*)d_in[26];
  const float* pbih  = (const float*)d_in[27];
  const float* pbhh  = (const float*)d_in[28];
  const float* plng  = (const float*)d_in[29];
  const float* plnb  = (const float*)d_in[30];
  const float* poww  = (const float*)d_in[31];
  const float* pob   = (const float*)d_in[32];
  const float* als   = (const float*)d_in[33];

  float* out = (float*)d_out;
  double* wsd = (double*)d_ws;
  float* wsf = (float*)(wsd + D_TOTAL);             // fp32 region
  float* w2f     = wsf + OF_PW2F;                   // [80][320]
  float* traj_hs = wsf + F_TOTAL;                   // [8][NTOT][32]
  float* gin     = traj_hs + (size_t)8*NTOT*32;     // [8][NSC][32][64]
  float* gh      = gin + (size_t)8*NTOT*32;         // [NTOT][32]

  k_prep<<<dim3(104), dim3(256), 0, stream>>>(
      pwhh, pwih, pbih, pbhh, plng, plnb, poww, pob,
      twih, twhh, tbih, tbhh, gwih, gwhh, gbih, gbhh, glng, glnb,
      gw0, gas0, gad0, gb0, gw1, gas1, gad1, gb1, wsd, wsf);
  k_traj<<<dim3(512), dim3(256), 0, stream>>>(obs, th0, tc0, wsd, traj_hs);
  k_gat<<<dim3(4096), dim3(256), 0, stream>>>(traj_hs, wsd, gin);
  k_graph<<<dim3(512), dim3(256), 0, stream>>>(gin, gh0, gc0, wsd, gh);
  k_pred<<<dim3(512), dim3(512), 0, stream>>>(traj_hs, gh, zn, obs, wsd, w2f, als, out);
}